// Round 8
// baseline (440.662 us; speedup 1.0000x reference)
//
#include <hip/hip_runtime.h>
#include <hip/hip_bf16.h>

typedef __hip_bfloat16 bf16;
typedef __attribute__((ext_vector_type(8))) short short8;
typedef __attribute__((ext_vector_type(4))) float f32x4;

#define HDIM 512
#define SLOPE 0.01f
#define BN_EPS 1e-5f
#define STRIPES 8

__device__ inline float bf2f(short s) {
    unsigned u = ((unsigned)(unsigned short)s) << 16;
    return __builtin_bit_cast(float, u);
}
__device__ inline unsigned short f2bfbits(float v) {
    bf16 h = __float2bfloat16(v);
    return (unsigned short)__builtin_bit_cast(short, h);
}

// packed edge record: src node + precomputed norm (single 8B load in gather loop)
struct EdgeRec { int src; float nm; };

// ---------------- dtype detection + gpart zero-init ----------------
__global__ void detect_types(const int* __restrict__ ei, const unsigned* __restrict__ xw,
                             int* __restrict__ flags, float* __restrict__ gpart) {
    __shared__ int nzhi, okbf;
    if (threadIdx.x == 0) { nzhi = 0; okbf = 0; }
    __syncthreads();
    int lo = 0, ok = 0;
    for (int i = threadIdx.x; i < 2048; i += 256)
        if (ei[2 * i + 1] != 0) lo++;
    for (int i = threadIdx.x; i < 1024; i += 256) {
        unsigned w = (xw[i] & 0xFFFFu) << 16;
        float av = fabsf(__builtin_bit_cast(float, w));
        if (av > 0.0009f && av < 64.0f) ok++;
    }
    for (int i = threadIdx.x; i < STRIPES * 2 * HDIM; i += 256) gpart[i] = 0.f;
    if (lo) atomicAdd(&nzhi, lo);
    if (ok) atomicAdd(&okbf, ok);
    __syncthreads();
    if (threadIdx.x == 0) {
        flags[0] = (nzhi == 0) ? 1 : 0;
        flags[1] = (okbf < 512) ? 1 : 0;
    }
}

// convert ei (2E) + batch (N) to int32, and count in-degrees from cols on the fly
__global__ void conv_all_idx(const int* __restrict__ ei, const int* __restrict__ batch,
                             int* __restrict__ ei32, int* __restrict__ batch32,
                             int* __restrict__ cnt, int e2, int n,
                             const int* __restrict__ flags) {
    int i = blockIdx.x * blockDim.x + threadIdx.x;
    int i64 = flags[0];
    if (i < e2) {
        int v = i64 ? (int)((const long long*)ei)[i] : ei[i];
        ei32[i] = v;
        if (i >= e2 / 2) atomicAdd(&cnt[v], 1);   // cols half
    } else if (i < e2 + n) {
        int j = i - e2;
        batch32[j] = i64 ? (int)((const long long*)batch)[j] : batch[j];
    }
}

// convert + transpose all weights and the final bias in one launch
__global__ void wt_conv_all(const void* __restrict__ W1, const void* __restrict__ W2,
                            const void* __restrict__ Wf, const void* __restrict__ bf_,
                            bf16* __restrict__ W1T, bf16* __restrict__ W2T,
                            bf16* __restrict__ WfT, bf16* __restrict__ bfbf,
                            const int* __restrict__ flags) {
    const int S1 = 128 * 512, S2 = 512 * 512, S3 = 512 * 256;
    int idx = blockIdx.x * 256 + threadIdx.x;
    bool f32 = flags[1] != 0;
    if (idx < S1) {
        int nn = idx / 128, k = idx - nn * 128;   // K=128, Nn=512
        float v = f32 ? ((const float*)W1)[(size_t)k * 512 + nn]
                      : __bfloat162float(((const bf16*)W1)[(size_t)k * 512 + nn]);
        W1T[idx] = __float2bfloat16(v);
    } else if (idx < S1 + S2) {
        int t = idx - S1;
        int nn = t / 512, k = t - nn * 512;       // K=512, Nn=512
        float v = f32 ? ((const float*)W2)[(size_t)k * 512 + nn]
                      : __bfloat162float(((const bf16*)W2)[(size_t)k * 512 + nn]);
        W2T[t] = __float2bfloat16(v);
    } else if (idx < S1 + S2 + S3) {
        int t = idx - S1 - S2;
        int nn = t / 512, k = t - nn * 512;       // K=512, Nn=256
        float v = f32 ? ((const float*)Wf)[(size_t)k * 256 + nn]
                      : __bfloat162float(((const bf16*)Wf)[(size_t)k * 256 + nn]);
        WfT[t] = __float2bfloat16(v);
    } else if (idx < S1 + S2 + S3 + 256) {
        int t = idx - S1 - S2 - S3;
        float v = f32 ? ((const float*)bf_)[t]
                      : __bfloat162float(((const bf16*)bf_)[t]);
        bfbf[t] = __float2bfloat16(v);
    }
}

// ---------------- parallel exclusive scan (3 kernels, 512 elems/block) -----------
// scan_part also finalizes degrees (dinv/selfw) from the same counts it loads —
// removes the separate finalize_deg dispatch from the serial preprocessing chain.
__global__ __launch_bounds__(256) void scan_part(
    const int* __restrict__ counts, int* __restrict__ offsets,
    int* __restrict__ bsum, float* __restrict__ dinv, float* __restrict__ selfw,
    int n)
{
    __shared__ int s[512];
    int b = blockIdx.x;
    int base = b * 512;
    int t = threadIdx.x;
    int c0 = (base + t       < n) ? counts[base + t]       : 0;
    int c1 = (base + t + 256 < n) ? counts[base + t + 256] : 0;
    s[t] = c0; s[t + 256] = c1;
    if (base + t < n) {
        float d = (float)c0 + 2.0f;
        dinv[base + t] = rsqrtf(d);
        selfw[base + t] = 2.0f / d;
    }
    if (base + t + 256 < n) {
        float d = (float)c1 + 2.0f;
        dinv[base + t + 256] = rsqrtf(d);
        selfw[base + t + 256] = 2.0f / d;
    }

    int offset = 1;
    for (int d = 256; d > 0; d >>= 1) {
        __syncthreads();
        if (t < d) {
            int ai = offset * (2 * t + 1) - 1;
            int bi = offset * (2 * t + 2) - 1;
            s[bi] += s[ai];
        }
        offset <<= 1;
    }
    __syncthreads();
    if (t == 0) { bsum[b] = s[511]; s[511] = 0; }
    for (int d = 1; d < 512; d <<= 1) {
        offset >>= 1;
        __syncthreads();
        if (t < d) {
            int ai = offset * (2 * t + 1) - 1;
            int bi = offset * (2 * t + 2) - 1;
            int tmp = s[ai]; s[ai] = s[bi]; s[bi] += tmp;
        }
    }
    __syncthreads();
    if (base + t < n)       offsets[base + t]       = s[t];
    if (base + t + 256 < n) offsets[base + t + 256] = s[t + 256];
}

__global__ __launch_bounds__(1024) void scan_tops(int* __restrict__ bsum, int nb) {
    __shared__ int s[1024];
    int t = threadIdx.x;
    s[t] = (t < nb) ? bsum[t] : 0;
    __syncthreads();
    for (int off = 1; off < 1024; off <<= 1) {
        int v = (t >= off) ? s[t - off] : 0;
        __syncthreads();
        s[t] += v;
        __syncthreads();
    }
    if (t < nb) bsum[t] = (t == 0) ? 0 : s[t - 1];   // exclusive
}

__global__ __launch_bounds__(256) void scan_add(
    int* __restrict__ offsets, const int* __restrict__ bsum, int n, int e)
{
    int b = blockIdx.x;
    int base = b * 512;
    int add = bsum[b];
    int t = threadIdx.x;
    if (base + t < n)       offsets[base + t]       += add;
    if (base + t + 256 < n) offsets[base + t + 256] += add;
    if (b == 0 && t == 0) offsets[n] = e;
}

// scatter edges into CSR order as packed {src, norm} records
__global__ void scatter_edges(const int* __restrict__ rows, const int* __restrict__ cols,
                              const int* __restrict__ offsets, int* __restrict__ cursor,
                              const float* __restrict__ dinv,
                              EdgeRec* __restrict__ er, int e)
{
    int i = blockIdx.x * blockDim.x + threadIdx.x;
    if (i < e) {
        int d = cols[i];
        int r = rows[i];
        int pos = offsets[d] + atomicAdd(&cursor[d], 1);
        EdgeRec rec;
        rec.src = r;
        rec.nm = dinv[d] * dinv[r];
        er[pos] = rec;
    }
}

// ------ m97-style GEMM, BK=32, TRUE XCD swizzle, LDS XOR-swizzle ------------------
// T4 counted-vmcnt 2-deep pipeline (round-7, +5%): raw s_barrier + s_waitcnt
// vmcnt(4); every inline waitcnt followed by sched_barrier(0) (rule #18).
// T1 XCD swizzle (this round): HW round-robins consecutive blockIdx across the
// 8 XCDs, so the previous "tiled id" mapping spread each 8-mblk A-panel's 4x
// re-read (one per nblk) over 8 non-coherent L2s -> served from L3 (~400cy).
// Remap id=(bid&7)*(nwg/8)+bid>>3: each XCD owns a CONTIGUOUS run of logical
// tiles -> A-panel re-reads hit its own L2 (~200cy). Bijective (all grids %8==0).
// Epilogue: C tile staged to LDS (q-XOR swizzle), 16B/lane stores.
// launch_bounds(256,4): (256,5) measured -17 µs/dispatch. Pipeline depth-3+ is
// LDS-blocked (48KB -> 3 blocks/CU; m132: occupancy cut regresses this structure).
#define GEMM_STAGE(boff, kk)                                                             \
    {                                                                                    \
        _Pragma("unroll")                                                                \
        for (int i_ = 0; i_ < 2; i_++) {                                                 \
            int c_ = wave * 2 + i_;                                                      \
            const bf16* ga_ = A  + (size_t)(m0 + c_ * 16 + lrow) * K + (kk) + lcol;      \
            const bf16* gb_ = BT + (size_t)(n0 + c_ * 16 + lrow) * K + (kk) + lcol;      \
            __builtin_amdgcn_global_load_lds(                                            \
                (const __attribute__((address_space(1))) unsigned*)ga_,                  \
                (__attribute__((address_space(3))) unsigned*)(smem + (boff) + c_ * 512), \
                16, 0, 0);                                                               \
            __builtin_amdgcn_global_load_lds(                                            \
                (const __attribute__((address_space(1))) unsigned*)gb_,                  \
                (__attribute__((address_space(3))) unsigned*)(smem + 8192 + (boff) + c_ * 512), \
                16, 0, 0);                                                               \
        }                                                                                \
    }

#define GEMM_COMPUTE(boff)                                                               \
    {                                                                                    \
        short8 a[4], b[4];                                                               \
        _Pragma("unroll")                                                                \
        for (int mi2 = 0; mi2 < 4; mi2++)                                                \
            a[mi2] = *(const short8*)&smem[(boff) + (wm + mi2 * 16 + r) * 32 + aoff];    \
        _Pragma("unroll")                                                                \
        for (int ni = 0; ni < 4; ni++)                                                   \
            b[ni] = *(const short8*)&smem[8192 + (boff) + (wn + ni * 16 + r) * 32 + aoff]; \
        _Pragma("unroll")                                                                \
        for (int mi2 = 0; mi2 < 4; mi2++)                                                \
            _Pragma("unroll")                                                            \
            for (int ni = 0; ni < 4; ni++)                                               \
                acc[mi2][ni] = __builtin_amdgcn_mfma_f32_16x16x32_bf16(                  \
                    a[mi2], b[ni], acc[mi2][ni], 0, 0, 0);                               \
    }

template<bool STATS>
__global__ __launch_bounds__(256, 4) void gemm_m97(
    const bf16* __restrict__ A, const bf16* __restrict__ BT,
    void* __restrict__ C, const bf16* __restrict__ bias,
    int M, int K, int N, const int* __restrict__ cf32,
    float* __restrict__ gpart, int MB)
{
    // layout: [0,4096)=As buf0, [4096,8192)=As buf1, [8192,12288)=Bs buf0,
    //         [12288,16384)=Bs buf1 — 32 KB total, reused as C tile in epilogue
    __shared__ bf16 smem[16384];

    // T1: bijective XCD chunking (gridDim.x % 8 == 0 by construction)
    int cpx = gridDim.x >> 3;
    int id = (blockIdx.x & 7) * cpx + (blockIdx.x >> 3);

    int NBN = N >> 7;
    int grp = id / (8 * NBN);
    int loc = id - grp * 8 * NBN;
    int mi = loc & 7;
    int nblk = loc >> 3;
    int mblk = grp * 8 + mi;
    if (mblk >= MB) return;

    int tid = threadIdx.x;
    int wave = tid >> 6, lane = tid & 63, q = lane >> 4, r = lane & 15;
    int wm = (wave >> 1) * 64, wn = (wave & 1) * 64;
    int m0 = mblk * 128, n0 = nblk * 128;
    bool c32 = cf32 && *cf32;

    int lrow = lane >> 2;
    int lcol = (((lane & 3) ^ ((lane >> 3) & 3)) * 8);   // XOR-swizzled source chunk
    int aoff = (q ^ ((r >> 1) & 3)) * 8;                 // fragment-read swizzle

    f32x4 acc[4][4];
#pragma unroll
    for (int mi2 = 0; mi2 < 4; mi2++)
#pragma unroll
        for (int ni = 0; ni < 4; ni++)
            acc[mi2][ni] = {0.f, 0.f, 0.f, 0.f};

    const int nK = K >> 5;

    // prologue: fill buffer 0 (4 loads in flight; first loop iter waits them
    // via vmcnt(4) after issuing its own 4 — no separate prologue barrier)
    GEMM_STAGE(0, 0);

    int cur = 0;
    for (int t = 1; t < nK; ++t) {
        GEMM_STAGE(cur ^ 4096, t * 32);   // issue next tile (8 outstanding/wave)
        asm volatile("s_waitcnt vmcnt(4)" ::: "memory");   // prev tile landed
        __builtin_amdgcn_sched_barrier(0);
        __builtin_amdgcn_s_barrier();     // all waves: cur buffer fully resident
        __builtin_amdgcn_sched_barrier(0);
        GEMM_COMPUTE(cur);                // ds_read + 16 MFMA (next loads in flight)
        asm volatile("s_waitcnt lgkmcnt(0)" ::: "memory"); // my ds_reads done
        __builtin_amdgcn_sched_barrier(0);
        __builtin_amdgcn_s_barrier();     // all waves done reading cur -> reusable
        __builtin_amdgcn_sched_barrier(0);
        cur ^= 4096;
    }
    asm volatile("s_waitcnt vmcnt(0)" ::: "memory");       // last tile landed
    __builtin_amdgcn_sched_barrier(0);
    __builtin_amdgcn_s_barrier();
    __builtin_amdgcn_sched_barrier(0);
    GEMM_COMPUTE(cur);                    // last tile, no prefetch

    if (!c32) {
        // ---- vectorized epilogue: stage C tile in LDS, write 16B/lane ----
        __syncthreads();             // full drain: all waves done with As/Bs
#pragma unroll
        for (int mi2 = 0; mi2 < 4; mi2++) {
#pragma unroll
            for (int ni = 0; ni < 4; ni++) {
                int lc = wn + ni * 16 + r;
                float bv = bias ? __bfloat162float(bias[n0 + lc]) : 0.f;
#pragma unroll
                for (int reg = 0; reg < 4; reg++) {
                    int lr = wm + mi2 * 16 + q * 4 + reg;
                    int bo = ((lr << 8) + (lc << 1)) ^ (q << 5);  // q-XOR: conflict-free
                    *(bf16*)((char*)smem + bo) = __float2bfloat16(acc[mi2][ni][reg] + bv);
                }
            }
        }
        __syncthreads();
#pragma unroll
        for (int pss = 0; pss < 8; pss++) {
            int off = pss * 4096 + tid * 16;
            int row = off >> 8;
            int cb = off & 255;
            int rb = cb ^ (((row >> 2) & 3) << 5);   // un-swizzle
            f32x4 v = *(const f32x4*)((const char*)smem + (row << 8) + rb);
            int gm = m0 + row;
            if (gm < M)
                *(f32x4*)((char*)C + (((size_t)gm * N + n0) << 1) + cb) = v;
        }
    } else {
        // f32 output path (head GEMM with f32 inputs): scalar stores
#pragma unroll
        for (int mi2 = 0; mi2 < 4; mi2++) {
#pragma unroll
            for (int ni = 0; ni < 4; ni++) {
                int gn = n0 + wn + ni * 16 + r;
                float bv = bias ? __bfloat162float(bias[gn]) : 0.f;
#pragma unroll
                for (int reg = 0; reg < 4; reg++) {
                    int gm = m0 + wm + mi2 * 16 + q * 4 + reg;
                    if (gm < M)
                        ((float*)C)[(size_t)gm * N + gn] = acc[mi2][ni][reg] + bv;
                }
            }
        }
    }

    if constexpr (STATS) {
        float* base = gpart + (size_t)(mblk & (STRIPES - 1)) * 2 * HDIM;
#pragma unroll
        for (int ni = 0; ni < 4; ni++) {
            float cs = 0.f, cq = 0.f;
#pragma unroll
            for (int mi2 = 0; mi2 < 4; mi2++)
#pragma unroll
                for (int reg = 0; reg < 4; reg++) {
                    int gm = m0 + wm + mi2 * 16 + q * 4 + reg;
                    if (gm < M) {
                        float v = acc[mi2][ni][reg];
                        cs += v; cq += v * v;
                    }
                }
            // reduce over q (lanes r, r+16, r+32, r+48 share column wn+ni*16+r)
            cs += __shfl_xor(cs, 16, 64);
            cs += __shfl_xor(cs, 32, 64);
            cq += __shfl_xor(cq, 16, 64);
            cq += __shfl_xor(cq, 32, 64);
            if (q == 0) {
                int c = n0 + wn + ni * 16 + r;
                atomicAdd(&base[c], cs);
                atomicAdd(&base[HDIM + c], cq);
            }
        }
    }
}

// ----- persistent CSR aggregation, 128-dim input -----------------------------------
// MLP-restructured: next-dst metadata+self-row prefetch, 4-wide edge chunks,
// 3-wide parallel tail (avg degree ~3 -> the tail IS the hot path).
#define AGG_DIN_BODY(LOADV)                                                            \
    int dst = gw;                                                                      \
    if (dst < n) {                                                                     \
        int s0 = offsets[dst], s1 = offsets[dst + 1];                                  \
        float sw = selfw[dst];                                                         \
        float h0, h1; LOADV(dst, h0, h1);                                              \
        while (dst < n) {                                                              \
            int nd = dst + nw;                                                         \
            int ns0 = 0, ns1 = 0; float nsw = 0.f, nh0 = 0.f, nh1 = 0.f;               \
            if (nd < n) {                                                              \
                ns0 = offsets[nd]; ns1 = offsets[nd + 1]; nsw = selfw[nd];             \
                LOADV(nd, nh0, nh1);                                                   \
            }                                                                          \
            float a0 = sw * h0, a1 = sw * h1;                                          \
            int p = s0;                                                                \
            for (; p + 3 < s1; p += 4) {                                               \
                EdgeRec e0 = er[p], e1 = er[p + 1], e2 = er[p + 2], e3 = er[p + 3];    \
                float x0, y0, x1, y1, x2, y2, x3, y3;                                  \
                LOADV(e0.src, x0, y0); LOADV(e1.src, x1, y1);                          \
                LOADV(e2.src, x2, y2); LOADV(e3.src, x3, y3);                          \
                a0 += e0.nm * x0 + e1.nm * x1 + e2.nm * x2 + e3.nm * x3;               \
                a1 += e0.nm * y0 + e1.nm * y1 + e2.nm * y2 + e3.nm * y3;               \
            }                                                                          \
            int rem = s1 - p;                                                          \
            if (rem > 0) {                                                             \
                EdgeRec e0 = er[p], e1 = e0, e2 = e0;                                  \
                if (rem > 1) e1 = er[p + 1];                                           \
                if (rem > 2) e2 = er[p + 2];                                           \
                float x0, y0, x1 = 0.f, y1 = 0.f, x2 = 0.f, y2 = 0.f;                  \
                LOADV(e0.src, x0, y0);                                                 \
                if (rem > 1) LOADV(e1.src, x1, y1);                                    \
                if (rem > 2) LOADV(e2.src, x2, y2);                                    \
                a0 += e0.nm * x0; a1 += e0.nm * y0;                                    \
                if (rem > 1) { a0 += e1.nm * x1; a1 += e1.nm * y1; }                   \
                if (rem > 2) { a0 += e2.nm * x2; a1 += e2.nm * y2; }                   \
            }                                                                          \
            ((unsigned*)out)[(size_t)dst * 64 + lane] =                                \
                (unsigned)f2bfbits(a0) | ((unsigned)f2bfbits(a1) << 16);               \
            dst = nd; s0 = ns0; s1 = ns1; sw = nsw; h0 = nh0; h1 = nh1;                \
        }                                                                              \
    }

#define LOADF32(idx, a, b) { float2 v_ = ((const float2*)x)[(size_t)(idx) * 64 + lane]; \
                             a = v_.x; b = v_.y; }
#define LOADBF(idx, a, b)  { unsigned u_ = ((const unsigned*)x)[(size_t)(idx) * 64 + lane]; \
                             a = bf2f((short)(u_ & 0xFFFF)); b = bf2f((short)(u_ >> 16)); }

__global__ __launch_bounds__(256) void agg_csr_din(
    const void* __restrict__ x, const int* __restrict__ offsets,
    const EdgeRec* __restrict__ er, const float* __restrict__ selfw,
    bf16* __restrict__ out, int n, const int* __restrict__ flags)
{
    int wave = threadIdx.x >> 6, lane = threadIdx.x & 63;
    int gw = blockIdx.x * 4 + wave;
    int nw = gridDim.x * 4;
    bool f32 = flags[1] != 0;
    if (f32) { AGG_DIN_BODY(LOADF32) } else { AGG_DIN_BODY(LOADBF) }
}

// -- persistent CSR aggregation (512-dim) with fused BN-affine+leaky ---------------
// Same MLP restructure: metadata+self-row prefetch, 4-wide chunks, 3-wide tail.
__device__ inline void bnlk8(const short8& v, const float* sc, const float* sh,
                             float* t) {
#pragma unroll
    for (int j = 0; j < 8; j++) {
        float u = sc[j] * bf2f(v[j]) + sh[j];
        t[j] = u > 0.f ? u : SLOPE * u;
    }
}

__global__ __launch_bounds__(256) void agg_csr_bn(
    const bf16* __restrict__ h, const int* __restrict__ offsets,
    const EdgeRec* __restrict__ er, const float* __restrict__ selfw,
    const float* __restrict__ scale, const float* __restrict__ shift,
    bf16* __restrict__ y, int n)
{
    int wave = threadIdx.x >> 6, lane = threadIdx.x & 63;
    int f0 = lane * 8;
    int gw = blockIdx.x * 4 + wave;
    int nw = gridDim.x * 4;

    float sc[8], sh[8];
#pragma unroll
    for (int j = 0; j < 8; j++) { sc[j] = scale[f0 + j]; sh[j] = shift[f0 + j]; }

    int dst = gw;
    if (dst >= n) return;
    int s0 = offsets[dst], s1 = offsets[dst + 1];
    float sw = selfw[dst];
    short8 hv = *(const short8*)(h + (size_t)dst * HDIM + f0);

    while (dst < n) {
        int nd = dst + nw;
        int ns0 = 0, ns1 = 0; float nsw = 0.f; short8 nhv = {};
        if (nd < n) {
            ns0 = offsets[nd]; ns1 = offsets[nd + 1]; nsw = selfw[nd];
            nhv = *(const short8*)(h + (size_t)nd * HDIM + f0);
        }

        float acc[8], t[8];
        bnlk8(hv, sc, sh, t);
#pragma unroll
        for (int j = 0; j < 8; j++) acc[j] = sw * t[j];

        int p = s0;
        for (; p + 3 < s1; p += 4) {
            EdgeRec e0 = er[p], e1 = er[p + 1], e2 = er[p + 2], e3 = er[p + 3];
            short8 v0 = *(const short8*)(h + (size_t)e0.src * HDIM + f0);
            short8 v1 = *(const short8*)(h + (size_t)e1.src * HDIM + f0);
            short8 v2 = *(const short8*)(h + (size_t)e2.src * HDIM + f0);
            short8 v3 = *(const short8*)(h + (size_t)e3.src * HDIM + f0);
            float t0[8], t1[8], t2[8], t3[8];
            bnlk8(v0, sc, sh, t0); bnlk8(v1, sc, sh, t1);
            bnlk8(v2, sc, sh, t2); bnlk8(v3, sc, sh, t3);
#pragma unroll
            for (int j = 0; j < 8; j++)
                acc[j] += e0.nm * t0[j] + e1.nm * t1[j] + e2.nm * t2[j] + e3.nm * t3[j];
        }
        int rem = s1 - p;
        if (rem > 0) {
            EdgeRec e0 = er[p], e1 = e0, e2 = e0;
            if (rem > 1) e1 = er[p + 1];
            if (rem > 2) e2 = er[p + 2];
            short8 v0 = *(const short8*)(h + (size_t)e0.src * HDIM + f0);
            short8 v1 = {}, v2 = {};
            if (rem > 1) v1 = *(const short8*)(h + (size_t)e1.src * HDIM + f0);
            if (rem > 2) v2 = *(const short8*)(h + (size_t)e2.src * HDIM + f0);
            float t0[8];
            bnlk8(v0, sc, sh, t0);
#pragma unroll
            for (int j = 0; j < 8; j++) acc[j] += e0.nm * t0[j];
            if (rem > 1) {
                float t1[8]; bnlk8(v1, sc, sh, t1);
#pragma unroll
                for (int j = 0; j < 8; j++) acc[j] += e1.nm * t1[j];
            }
            if (rem > 2) {
                float t2[8]; bnlk8(v2, sc, sh, t2);
#pragma unroll
                for (int j = 0; j < 8; j++) acc[j] += e2.nm * t2[j];
            }
        }

        short8 o;
#pragma unroll
        for (int j = 0; j < 8; j++) ((bf16*)&o)[j] = __float2bfloat16(acc[j]);
        *(short8*)(y + (size_t)dst * HDIM + f0) = o;

        dst = nd; s0 = ns0; s1 = ns1; sw = nsw; hv = nhv;
    }
}

// ------ BN coeffs from striped partials; re-zeros gpart for the next layer --------
__global__ void bn_final(float* __restrict__ gpart,
                         const void* __restrict__ gamma, const void* __restrict__ beta,
                         float* __restrict__ scale, float* __restrict__ shift,
                         float invN, const int* __restrict__ flags)
{
    int f = threadIdx.x;
    float s = 0.f, q = 0.f;
#pragma unroll
    for (int k = 0; k < STRIPES; k++) {
        s += gpart[(size_t)k * 2 * HDIM + f];
        q += gpart[(size_t)k * 2 * HDIM + HDIM + f];
        gpart[(size_t)k * 2 * HDIM + f] = 0.f;
        gpart[(size_t)k * 2 * HDIM + HDIM + f] = 0.f;
    }
    float g = flags[1] ? ((const float*)gamma)[f]
                       : __bfloat162float(((const bf16*)gamma)[f]);
    float b = flags[1] ? ((const float*)beta)[f]
                       : __bfloat162float(((const bf16*)beta)[f]);
    float mu = s * invN;
    float var = fmaxf(q * invN - mu * mu, 0.f);
    float inv = rsqrtf(var + BN_EPS);
    float sc = g * inv;
    scale[f] = sc;
    shift[f] = b - mu * sc;
}

// ---- pooling: wave per graph, 16B/lane loads, fused BN+leaky (monotone) ----------
__global__ __launch_bounds__(256) void pool_fused(
    const bf16* __restrict__ y, const int* __restrict__ batch,
    const float* __restrict__ scale, const float* __restrict__ shift,
    bf16* __restrict__ pooled, int n, int G)
{
    int wave = threadIdx.x >> 6, lane = threadIdx.x & 63;
    int g = blockIdx.x * 4 + wave;
    if (g >= G) return;
    int f0 = lane * 8;

    int lo = 0, hi = n;
    while (lo < hi) { int mid = (lo + hi) >> 1; if (batch[mid] < g) lo = mid + 1; else hi = mid; }
    int s = lo;
    hi = n;
    while (lo < hi) { int mid = (lo + hi) >> 1; if (batch[mid] <= g) lo = mid + 1; else hi = mid; }
    int e = lo;

    float mx[8], mn[8];
#pragma unroll
    for (int j = 0; j < 8; j++) { mx[j] = -3.0e38f; mn[j] = 3.0e38f; }

    int rr = s;
    for (; rr + 1 < e; rr += 2) {
        short8 v0 = *(const short8*)(y + (size_t)rr * HDIM + f0);
        short8 v1 = *(const short8*)(y + (size_t)(rr + 1) * HDIM + f0);
#pragma unroll
        for (int j = 0; j < 8; j++) {
            float a = bf2f(v0[j]), b = bf2f(v1[j]);
            mx[j] = fmaxf(mx[j], fmaxf(a, b));
            mn[j] = fminf(mn[j], fminf(a, b));
        }
    }
    if (rr < e) {
        short8 v0 = *(const short8*)(y + (size_t)rr * HDIM + f0);
#pragma unroll
        for (int j = 0; j < 8; j++) {
            float a = bf2f(v0[j]);
            mx[j] = fmaxf(mx[j], a);
            mn[j] = fminf(mn[j], a);
        }
    }

    short8 o;
#pragma unroll
    for (int j = 0; j < 8; j++) {
        float outv = 0.f;
        if (s < e) {
            float sc = scale[f0 + j];
            float t = sc * (sc >= 0.f ? mx[j] : mn[j]) + shift[f0 + j];
            outv = t > 0.f ? t : SLOPE * t;
        }
        ((bf16*)&o)[j] = __float2bfloat16(outv);
    }
    *(short8*)(pooled + (size_t)g * HDIM + f0) = o;
}

// ---------------- orchestration --------------------------------------------------
extern "C" void kernel_launch(void* const* d_in, const int* in_sizes, int n_in,
                              void* d_out, int out_size, void* d_ws, size_t ws_size,
                              hipStream_t stream)
{
    const void* x     = d_in[0];
    const int*  ei    = (const int*)d_in[1];
    const int*  batch = (const int*)d_in[2];
    // d_in[4]=b1, d_in[8]=b2 cancel in training-mode BatchNorm — unused.

    const int N   = in_sizes[2];
    const int E   = in_sizes[1] / 2;
    const int DIN = 128;
    const int OUT = 256;
    const int G   = out_size / OUT;
    const int Mp  = (N + 127) & ~127;
    const int MB  = Mp / 128;
    const int MB8 = (MB + 7) & ~7;

    // workspace carve — ~238 MB
    char* p = (char*)d_ws;
    bf16* B1     = (bf16*)p;  p += (size_t)Mp * HDIM * sizeof(bf16);
    bf16* B2     = (bf16*)p;  p += (size_t)Mp * HDIM * sizeof(bf16);
    bf16* Q      = (bf16*)p;  p += (size_t)Mp * DIN * sizeof(bf16);
    bf16* W1T    = (bf16*)p;  p += (size_t)HDIM * DIN * sizeof(bf16);
    bf16* W2T    = (bf16*)p;  p += (size_t)HDIM * HDIM * sizeof(bf16);
    bf16* WfT    = (bf16*)p;  p += (size_t)OUT * HDIM * sizeof(bf16);
    bf16* bfbf   = (bf16*)p;  p += 512 * sizeof(bf16);
    int* ei32    = (int*)p;   p += (size_t)2 * E * sizeof(int);
    int* batch32 = (int*)p;   p += (size_t)N * sizeof(int);
    float* dinv  = (float*)p; p += (size_t)N * sizeof(float);
    float* selfw = (float*)p; p += (size_t)N * sizeof(float);
    int* offsets = (int*)p;   p += (size_t)(N + 4) * sizeof(int);
    int* cursor  = (int*)p;   p += (size_t)N * sizeof(int);
    EdgeRec* er  = (EdgeRec*)p; p += (size_t)E * sizeof(EdgeRec);
    int* bsum    = (int*)p;   p += 1024 * sizeof(int);
    float* gpart = (float*)p; p += (size_t)STRIPES * 2 * HDIM * sizeof(float);
    float* sc1   = (float*)p; p += HDIM * sizeof(float);
    float* sh1   = (float*)p; p += HDIM * sizeof(float);
    float* sc2   = (float*)p; p += HDIM * sizeof(float);
    float* sh2   = (float*)p; p += HDIM * sizeof(float);
    int* flags   = (int*)p;   p += 4 * sizeof(int);

    // ---- detection (+gpart zero) + fused conversions + degree count ----
    detect_types<<<1, 256, 0, stream>>>(ei, (const unsigned*)x, flags, gpart);
    hipMemsetAsync(cursor, 0, (size_t)N * sizeof(int), stream);
    conv_all_idx<<<(2 * E + N + 255) / 256, 256, 0, stream>>>(
        ei, batch, ei32, batch32, cursor, 2 * E, N, flags);
    wt_conv_all<<<(128 * 512 + 512 * 512 + 512 * 256 + 256 + 255) / 256, 256, 0, stream>>>(
        d_in[3], d_in[7], d_in[11], d_in[12], W1T, W2T, WfT, bfbf, flags);

    const int* rows = ei32;
    const int* cols = ei32 + E;

    // ---- CSR + degrees (fused into scan_part) + packed edge records ----
    int nb = (N + 511) / 512;
    scan_part<<<nb, 256, 0, stream>>>(cursor, offsets, bsum, dinv, selfw, N);
    scan_tops<<<1, 1024, 0, stream>>>(bsum, nb);
    scan_add<<<nb, 256, 0, stream>>>(offsets, bsum, N, E);
    hipMemsetAsync(cursor, 0, (size_t)N * sizeof(int), stream);
    scatter_edges<<<(E + 255) / 256, 256, 0, stream>>>(rows, cols, offsets, cursor,
                                                       dinv, er, E);

    int gemm_blocks = MB8 * (HDIM / 128);

    // ---- layer 1: aggregate x (agg is linear), GEMM w/ fused stats ----
    agg_csr_din<<<2048, 256, 0, stream>>>(x, offsets, er, selfw, Q, N, flags);
    gemm_m97<true><<<gemm_blocks, 256, 0, stream>>>(
        Q, W1T, B2, nullptr, N, DIN, HDIM, nullptr, gpart, MB);
    bn_final<<<1, HDIM, 0, stream>>>(gpart, d_in[5], d_in[6], sc1, sh1, 1.0f / N, flags);

    // ---- layer 2: aggregate RAW conv1 output w/ fused BN+leaky, GEMM w/ stats ----
    agg_csr_bn<<<2048, 256, 0, stream>>>(B2, offsets, er, selfw, sc1, sh1, B1, N);
    gemm_m97<true><<<gemm_blocks, 256, 0, stream>>>(
        B1, W2T, B2, nullptr, N, HDIM, HDIM, nullptr, gpart, MB);
    bn_final<<<1, HDIM, 0, stream>>>(gpart, d_in[9], d_in[10], sc2, sh2, 1.0f / N, flags);

    // ---- pool (wave/graph, fused BN+leaky) + head GEMM ----
    pool_fused<<<(G + 3) / 4, 256, 0, stream>>>(B2, batch32, sc2, sh2, Q, N, G);
    gemm_m97<false><<<(G / 128) * (OUT / 128), 256, 0, stream>>>(
        Q, WfT, d_out, bfbf, G, HDIM, OUT, flags + 1, nullptr, G / 128);
}

// Round 9
// 432.017 us; speedup vs baseline: 1.0200x; 1.0200x over previous
//
#include <hip/hip_runtime.h>
#include <hip/hip_bf16.h>

typedef __hip_bfloat16 bf16;
typedef __attribute__((ext_vector_type(8))) short short8;
typedef __attribute__((ext_vector_type(4))) float f32x4;

#define HDIM 512
#define SLOPE 0.01f
#define BN_EPS 1e-5f
#define STRIPES 8

__device__ inline float bf2f(short s) {
    unsigned u = ((unsigned)(unsigned short)s) << 16;
    return __builtin_bit_cast(float, u);
}
__device__ inline unsigned short f2bfbits(float v) {
    bf16 h = __float2bfloat16(v);
    return (unsigned short)__builtin_bit_cast(short, h);
}

// packed edge record: src node + precomputed norm (single 8B load in gather loop)
struct EdgeRec { int src; float nm; };

// ---------------- dtype detection + gpart zero-init ----------------
__global__ void detect_types(const int* __restrict__ ei, const unsigned* __restrict__ xw,
                             int* __restrict__ flags, float* __restrict__ gpart) {
    __shared__ int nzhi, okbf;
    if (threadIdx.x == 0) { nzhi = 0; okbf = 0; }
    __syncthreads();
    int lo = 0, ok = 0;
    for (int i = threadIdx.x; i < 2048; i += 256)
        if (ei[2 * i + 1] != 0) lo++;
    for (int i = threadIdx.x; i < 1024; i += 256) {
        unsigned w = (xw[i] & 0xFFFFu) << 16;
        float av = fabsf(__builtin_bit_cast(float, w));
        if (av > 0.0009f && av < 64.0f) ok++;
    }
    for (int i = threadIdx.x; i < STRIPES * 2 * HDIM; i += 256) gpart[i] = 0.f;
    if (lo) atomicAdd(&nzhi, lo);
    if (ok) atomicAdd(&okbf, ok);
    __syncthreads();
    if (threadIdx.x == 0) {
        flags[0] = (nzhi == 0) ? 1 : 0;
        flags[1] = (okbf < 512) ? 1 : 0;
    }
}

// convert ei (2E) + batch (N) to int32, and count in-degrees from cols on the fly
__global__ void conv_all_idx(const int* __restrict__ ei, const int* __restrict__ batch,
                             int* __restrict__ ei32, int* __restrict__ batch32,
                             int* __restrict__ cnt, int e2, int n,
                             const int* __restrict__ flags) {
    int i = blockIdx.x * blockDim.x + threadIdx.x;
    int i64 = flags[0];
    if (i < e2) {
        int v = i64 ? (int)((const long long*)ei)[i] : ei[i];
        ei32[i] = v;
        if (i >= e2 / 2) atomicAdd(&cnt[v], 1);   // cols half
    } else if (i < e2 + n) {
        int j = i - e2;
        batch32[j] = i64 ? (int)((const long long*)batch)[j] : batch[j];
    }
}

// convert + transpose all weights and the final bias in one launch
__global__ void wt_conv_all(const void* __restrict__ W1, const void* __restrict__ W2,
                            const void* __restrict__ Wf, const void* __restrict__ bf_,
                            bf16* __restrict__ W1T, bf16* __restrict__ W2T,
                            bf16* __restrict__ WfT, bf16* __restrict__ bfbf,
                            const int* __restrict__ flags) {
    const int S1 = 128 * 512, S2 = 512 * 512, S3 = 512 * 256;
    int idx = blockIdx.x * 256 + threadIdx.x;
    bool f32 = flags[1] != 0;
    if (idx < S1) {
        int nn = idx / 128, k = idx - nn * 128;   // K=128, Nn=512
        float v = f32 ? ((const float*)W1)[(size_t)k * 512 + nn]
                      : __bfloat162float(((const bf16*)W1)[(size_t)k * 512 + nn]);
        W1T[idx] = __float2bfloat16(v);
    } else if (idx < S1 + S2) {
        int t = idx - S1;
        int nn = t / 512, k = t - nn * 512;       // K=512, Nn=512
        float v = f32 ? ((const float*)W2)[(size_t)k * 512 + nn]
                      : __bfloat162float(((const bf16*)W2)[(size_t)k * 512 + nn]);
        W2T[t] = __float2bfloat16(v);
    } else if (idx < S1 + S2 + S3) {
        int t = idx - S1 - S2;
        int nn = t / 512, k = t - nn * 512;       // K=512, Nn=256
        float v = f32 ? ((const float*)Wf)[(size_t)k * 256 + nn]
                      : __bfloat162float(((const bf16*)Wf)[(size_t)k * 256 + nn]);
        WfT[t] = __float2bfloat16(v);
    } else if (idx < S1 + S2 + S3 + 256) {
        int t = idx - S1 - S2 - S3;
        float v = f32 ? ((const float*)bf_)[t]
                      : __bfloat162float(((const bf16*)bf_)[t]);
        bfbf[t] = __float2bfloat16(v);
    }
}

// ---------------- parallel exclusive scan (3 kernels, 512 elems/block) -----------
// scan_part also finalizes degrees (dinv/selfw) from the same counts it loads —
// removes the separate finalize_deg dispatch from the serial preprocessing chain.
__global__ __launch_bounds__(256) void scan_part(
    const int* __restrict__ counts, int* __restrict__ offsets,
    int* __restrict__ bsum, float* __restrict__ dinv, float* __restrict__ selfw,
    int n)
{
    __shared__ int s[512];
    int b = blockIdx.x;
    int base = b * 512;
    int t = threadIdx.x;
    int c0 = (base + t       < n) ? counts[base + t]       : 0;
    int c1 = (base + t + 256 < n) ? counts[base + t + 256] : 0;
    s[t] = c0; s[t + 256] = c1;
    if (base + t < n) {
        float d = (float)c0 + 2.0f;
        dinv[base + t] = rsqrtf(d);
        selfw[base + t] = 2.0f / d;
    }
    if (base + t + 256 < n) {
        float d = (float)c1 + 2.0f;
        dinv[base + t + 256] = rsqrtf(d);
        selfw[base + t + 256] = 2.0f / d;
    }

    int offset = 1;
    for (int d = 256; d > 0; d >>= 1) {
        __syncthreads();
        if (t < d) {
            int ai = offset * (2 * t + 1) - 1;
            int bi = offset * (2 * t + 2) - 1;
            s[bi] += s[ai];
        }
        offset <<= 1;
    }
    __syncthreads();
    if (t == 0) { bsum[b] = s[511]; s[511] = 0; }
    for (int d = 1; d < 512; d <<= 1) {
        offset >>= 1;
        __syncthreads();
        if (t < d) {
            int ai = offset * (2 * t + 1) - 1;
            int bi = offset * (2 * t + 2) - 1;
            int tmp = s[ai]; s[ai] = s[bi]; s[bi] += tmp;
        }
    }
    __syncthreads();
    if (base + t < n)       offsets[base + t]       = s[t];
    if (base + t + 256 < n) offsets[base + t + 256] = s[t + 256];
}

__global__ __launch_bounds__(1024) void scan_tops(int* __restrict__ bsum, int nb) {
    __shared__ int s[1024];
    int t = threadIdx.x;
    s[t] = (t < nb) ? bsum[t] : 0;
    __syncthreads();
    for (int off = 1; off < 1024; off <<= 1) {
        int v = (t >= off) ? s[t - off] : 0;
        __syncthreads();
        s[t] += v;
        __syncthreads();
    }
    if (t < nb) bsum[t] = (t == 0) ? 0 : s[t - 1];   // exclusive
}

__global__ __launch_bounds__(256) void scan_add(
    int* __restrict__ offsets, const int* __restrict__ bsum, int n, int e)
{
    int b = blockIdx.x;
    int base = b * 512;
    int add = bsum[b];
    int t = threadIdx.x;
    if (base + t < n)       offsets[base + t]       += add;
    if (base + t + 256 < n) offsets[base + t + 256] += add;
    if (b == 0 && t == 0) offsets[n] = e;
}

// scatter edges into CSR order as packed {src, norm} records
__global__ void scatter_edges(const int* __restrict__ rows, const int* __restrict__ cols,
                              const int* __restrict__ offsets, int* __restrict__ cursor,
                              const float* __restrict__ dinv,
                              EdgeRec* __restrict__ er, int e)
{
    int i = blockIdx.x * blockDim.x + threadIdx.x;
    if (i < e) {
        int d = cols[i];
        int r = rows[i];
        int pos = offsets[d] + atomicAdd(&cursor[d], 1);
        EdgeRec rec;
        rec.src = r;
        rec.nm = dinv[d] * dinv[r];
        er[pos] = rec;
    }
}

// ------ m97-style GEMM, BK=32, natural grid order, LDS XOR-swizzle ----------------
// T4 counted-vmcnt 2-deep pipeline (round-7, +5%): raw s_barrier + s_waitcnt
// vmcnt(4); every inline waitcnt followed by sched_barrier(0) (rule #18).
// GRID MAPPING NOTE (round-8 lesson): bid = grp*32 + nblk*8 + mi with natural
// round-robin dispatch puts the 4 nblk-siblings of an mblk exactly 8 bids apart
// -> SAME XCD -> A-panel 4x reuse is already L2-local. An explicit XCD chunking
// remap measured -8 µs/dispatch (FETCH +4 MB): do NOT re-add without A/B.
// Epilogue: C tile staged to LDS (q-XOR swizzle), 16B/lane stores.
// launch_bounds(256,4): (256,5) measured -17 µs/dispatch. Pipeline depth-3+ is
// LDS-blocked (48KB -> 3 blocks/CU; m132: occupancy cut regresses this structure).
#define GEMM_STAGE(boff, kk)                                                             \
    {                                                                                    \
        _Pragma("unroll")                                                                \
        for (int i_ = 0; i_ < 2; i_++) {                                                 \
            int c_ = wave * 2 + i_;                                                      \
            const bf16* ga_ = A  + (size_t)(m0 + c_ * 16 + lrow) * K + (kk) + lcol;      \
            const bf16* gb_ = BT + (size_t)(n0 + c_ * 16 + lrow) * K + (kk) + lcol;      \
            __builtin_amdgcn_global_load_lds(                                            \
                (const __attribute__((address_space(1))) unsigned*)ga_,                  \
                (__attribute__((address_space(3))) unsigned*)(smem + (boff) + c_ * 512), \
                16, 0, 0);                                                               \
            __builtin_amdgcn_global_load_lds(                                            \
                (const __attribute__((address_space(1))) unsigned*)gb_,                  \
                (__attribute__((address_space(3))) unsigned*)(smem + 8192 + (boff) + c_ * 512), \
                16, 0, 0);                                                               \
        }                                                                                \
    }

#define GEMM_COMPUTE(boff)                                                               \
    {                                                                                    \
        short8 a[4], b[4];                                                               \
        _Pragma("unroll")                                                                \
        for (int mi2 = 0; mi2 < 4; mi2++)                                                \
            a[mi2] = *(const short8*)&smem[(boff) + (wm + mi2 * 16 + r) * 32 + aoff];    \
        _Pragma("unroll")                                                                \
        for (int ni = 0; ni < 4; ni++)                                                   \
            b[ni] = *(const short8*)&smem[8192 + (boff) + (wn + ni * 16 + r) * 32 + aoff]; \
        _Pragma("unroll")                                                                \
        for (int mi2 = 0; mi2 < 4; mi2++)                                                \
            _Pragma("unroll")                                                            \
            for (int ni = 0; ni < 4; ni++)                                               \
                acc[mi2][ni] = __builtin_amdgcn_mfma_f32_16x16x32_bf16(                  \
                    a[mi2], b[ni], acc[mi2][ni], 0, 0, 0);                               \
    }

template<bool STATS>
__global__ __launch_bounds__(256, 4) void gemm_m97(
    const bf16* __restrict__ A, const bf16* __restrict__ BT,
    void* __restrict__ C, const bf16* __restrict__ bias,
    int M, int K, int N, const int* __restrict__ cf32,
    float* __restrict__ gpart, int MB)
{
    // layout: [0,4096)=As buf0, [4096,8192)=As buf1, [8192,12288)=Bs buf0,
    //         [12288,16384)=Bs buf1 — 32 KB total, reused as C tile in epilogue
    __shared__ bf16 smem[16384];

    int NBN = N >> 7;
    int id = blockIdx.x;
    int grp = id / (8 * NBN);
    int loc = id - grp * 8 * NBN;
    int mi = loc & 7;
    int nblk = loc >> 3;
    int mblk = grp * 8 + mi;
    if (mblk >= MB) return;

    int tid = threadIdx.x;
    int wave = tid >> 6, lane = tid & 63, q = lane >> 4, r = lane & 15;
    int wm = (wave >> 1) * 64, wn = (wave & 1) * 64;
    int m0 = mblk * 128, n0 = nblk * 128;
    bool c32 = cf32 && *cf32;

    int lrow = lane >> 2;
    int lcol = (((lane & 3) ^ ((lane >> 3) & 3)) * 8);   // XOR-swizzled source chunk
    int aoff = (q ^ ((r >> 1) & 3)) * 8;                 // fragment-read swizzle

    f32x4 acc[4][4];
#pragma unroll
    for (int mi2 = 0; mi2 < 4; mi2++)
#pragma unroll
        for (int ni = 0; ni < 4; ni++)
            acc[mi2][ni] = {0.f, 0.f, 0.f, 0.f};

    const int nK = K >> 5;

    // prologue: fill buffer 0 (4 loads in flight; first loop iter waits them
    // via vmcnt(4) after issuing its own 4 — no separate prologue barrier)
    GEMM_STAGE(0, 0);

    int cur = 0;
    for (int t = 1; t < nK; ++t) {
        GEMM_STAGE(cur ^ 4096, t * 32);   // issue next tile (8 outstanding/wave)
        asm volatile("s_waitcnt vmcnt(4)" ::: "memory");   // prev tile landed
        __builtin_amdgcn_sched_barrier(0);
        __builtin_amdgcn_s_barrier();     // all waves: cur buffer fully resident
        __builtin_amdgcn_sched_barrier(0);
        GEMM_COMPUTE(cur);                // ds_read + 16 MFMA (next loads in flight)
        asm volatile("s_waitcnt lgkmcnt(0)" ::: "memory"); // my ds_reads done
        __builtin_amdgcn_sched_barrier(0);
        __builtin_amdgcn_s_barrier();     // all waves done reading cur -> reusable
        __builtin_amdgcn_sched_barrier(0);
        cur ^= 4096;
    }
    asm volatile("s_waitcnt vmcnt(0)" ::: "memory");       // last tile landed
    __builtin_amdgcn_sched_barrier(0);
    __builtin_amdgcn_s_barrier();
    __builtin_amdgcn_sched_barrier(0);
    GEMM_COMPUTE(cur);                    // last tile, no prefetch

    if (!c32) {
        // ---- vectorized epilogue: stage C tile in LDS, write 16B/lane ----
        __syncthreads();             // full drain: all waves done with As/Bs
#pragma unroll
        for (int mi2 = 0; mi2 < 4; mi2++) {
#pragma unroll
            for (int ni = 0; ni < 4; ni++) {
                int lc = wn + ni * 16 + r;
                float bv = bias ? __bfloat162float(bias[n0 + lc]) : 0.f;
#pragma unroll
                for (int reg = 0; reg < 4; reg++) {
                    int lr = wm + mi2 * 16 + q * 4 + reg;
                    int bo = ((lr << 8) + (lc << 1)) ^ (q << 5);  // q-XOR: conflict-free
                    *(bf16*)((char*)smem + bo) = __float2bfloat16(acc[mi2][ni][reg] + bv);
                }
            }
        }
        __syncthreads();
#pragma unroll
        for (int pss = 0; pss < 8; pss++) {
            int off = pss * 4096 + tid * 16;
            int row = off >> 8;
            int cb = off & 255;
            int rb = cb ^ (((row >> 2) & 3) << 5);   // un-swizzle
            f32x4 v = *(const f32x4*)((const char*)smem + (row << 8) + rb);
            int gm = m0 + row;
            if (gm < M)
                *(f32x4*)((char*)C + (((size_t)gm * N + n0) << 1) + cb) = v;
        }
    } else {
        // f32 output path (head GEMM with f32 inputs): scalar stores
#pragma unroll
        for (int mi2 = 0; mi2 < 4; mi2++) {
#pragma unroll
            for (int ni = 0; ni < 4; ni++) {
                int gn = n0 + wn + ni * 16 + r;
                float bv = bias ? __bfloat162float(bias[gn]) : 0.f;
#pragma unroll
                for (int reg = 0; reg < 4; reg++) {
                    int gm = m0 + wm + mi2 * 16 + q * 4 + reg;
                    if (gm < M)
                        ((float*)C)[(size_t)gm * N + gn] = acc[mi2][ni][reg] + bv;
                }
            }
        }
    }

    if constexpr (STATS) {
        float* base = gpart + (size_t)(mblk & (STRIPES - 1)) * 2 * HDIM;
#pragma unroll
        for (int ni = 0; ni < 4; ni++) {
            float cs = 0.f, cq = 0.f;
#pragma unroll
            for (int mi2 = 0; mi2 < 4; mi2++)
#pragma unroll
                for (int reg = 0; reg < 4; reg++) {
                    int gm = m0 + wm + mi2 * 16 + q * 4 + reg;
                    if (gm < M) {
                        float v = acc[mi2][ni][reg];
                        cs += v; cq += v * v;
                    }
                }
            // reduce over q (lanes r, r+16, r+32, r+48 share column wn+ni*16+r)
            cs += __shfl_xor(cs, 16, 64);
            cs += __shfl_xor(cs, 32, 64);
            cq += __shfl_xor(cq, 16, 64);
            cq += __shfl_xor(cq, 32, 64);
            if (q == 0) {
                int c = n0 + wn + ni * 16 + r;
                atomicAdd(&base[c], cs);
                atomicAdd(&base[HDIM + c], cq);
            }
        }
    }
}

// ----- persistent CSR aggregation, 128-dim input -----------------------------------
// MLP-restructured: next-dst metadata+self-row prefetch, 4-wide edge chunks,
// 3-wide parallel tail (avg degree ~3 -> the tail IS the hot path).
#define AGG_DIN_BODY(LOADV)                                                            \
    int dst = gw;                                                                      \
    if (dst < n) {                                                                     \
        int s0 = offsets[dst], s1 = offsets[dst + 1];                                  \
        float sw = selfw[dst];                                                         \
        float h0, h1; LOADV(dst, h0, h1);                                              \
        while (dst < n) {                                                              \
            int nd = dst + nw;                                                         \
            int ns0 = 0, ns1 = 0; float nsw = 0.f, nh0 = 0.f, nh1 = 0.f;               \
            if (nd < n) {                                                              \
                ns0 = offsets[nd]; ns1 = offsets[nd + 1]; nsw = selfw[nd];             \
                LOADV(nd, nh0, nh1);                                                   \
            }                                                                          \
            float a0 = sw * h0, a1 = sw * h1;                                          \
            int p = s0;                                                                \
            for (; p + 3 < s1; p += 4) {                                               \
                EdgeRec e0 = er[p], e1 = er[p + 1], e2 = er[p + 2], e3 = er[p + 3];    \
                float x0, y0, x1, y1, x2, y2, x3, y3;                                  \
                LOADV(e0.src, x0, y0); LOADV(e1.src, x1, y1);                          \
                LOADV(e2.src, x2, y2); LOADV(e3.src, x3, y3);                          \
                a0 += e0.nm * x0 + e1.nm * x1 + e2.nm * x2 + e3.nm * x3;               \
                a1 += e0.nm * y0 + e1.nm * y1 + e2.nm * y2 + e3.nm * y3;               \
            }                                                                          \
            int rem = s1 - p;                                                          \
            if (rem > 0) {                                                             \
                EdgeRec e0 = er[p], e1 = e0, e2 = e0;                                  \
                if (rem > 1) e1 = er[p + 1];                                           \
                if (rem > 2) e2 = er[p + 2];                                           \
                float x0, y0, x1 = 0.f, y1 = 0.f, x2 = 0.f, y2 = 0.f;                  \
                LOADV(e0.src, x0, y0);                                                 \
                if (rem > 1) LOADV(e1.src, x1, y1);                                    \
                if (rem > 2) LOADV(e2.src, x2, y2);                                    \
                a0 += e0.nm * x0; a1 += e0.nm * y0;                                    \
                if (rem > 1) { a0 += e1.nm * x1; a1 += e1.nm * y1; }                   \
                if (rem > 2) { a0 += e2.nm * x2; a1 += e2.nm * y2; }                   \
            }                                                                          \
            ((unsigned*)out)[(size_t)dst * 64 + lane] =                                \
                (unsigned)f2bfbits(a0) | ((unsigned)f2bfbits(a1) << 16);               \
            dst = nd; s0 = ns0; s1 = ns1; sw = nsw; h0 = nh0; h1 = nh1;                \
        }                                                                              \
    }

#define LOADF32(idx, a, b) { float2 v_ = ((const float2*)x)[(size_t)(idx) * 64 + lane]; \
                             a = v_.x; b = v_.y; }
#define LOADBF(idx, a, b)  { unsigned u_ = ((const unsigned*)x)[(size_t)(idx) * 64 + lane]; \
                             a = bf2f((short)(u_ & 0xFFFF)); b = bf2f((short)(u_ >> 16)); }

__global__ __launch_bounds__(256) void agg_csr_din(
    const void* __restrict__ x, const int* __restrict__ offsets,
    const EdgeRec* __restrict__ er, const float* __restrict__ selfw,
    bf16* __restrict__ out, int n, const int* __restrict__ flags)
{
    int wave = threadIdx.x >> 6, lane = threadIdx.x & 63;
    int gw = blockIdx.x * 4 + wave;
    int nw = gridDim.x * 4;
    bool f32 = flags[1] != 0;
    if (f32) { AGG_DIN_BODY(LOADF32) } else { AGG_DIN_BODY(LOADBF) }
}

// -- persistent CSR aggregation (512-dim) with fused BN-affine+leaky ---------------
// Same MLP restructure: metadata+self-row prefetch, 4-wide chunks, 3-wide tail.
__device__ inline void bnlk8(const short8& v, const float* sc, const float* sh,
                             float* t) {
#pragma unroll
    for (int j = 0; j < 8; j++) {
        float u = sc[j] * bf2f(v[j]) + sh[j];
        t[j] = u > 0.f ? u : SLOPE * u;
    }
}

__global__ __launch_bounds__(256) void agg_csr_bn(
    const bf16* __restrict__ h, const int* __restrict__ offsets,
    const EdgeRec* __restrict__ er, const float* __restrict__ selfw,
    const float* __restrict__ scale, const float* __restrict__ shift,
    bf16* __restrict__ y, int n)
{
    int wave = threadIdx.x >> 6, lane = threadIdx.x & 63;
    int f0 = lane * 8;
    int gw = blockIdx.x * 4 + wave;
    int nw = gridDim.x * 4;

    float sc[8], sh[8];
#pragma unroll
    for (int j = 0; j < 8; j++) { sc[j] = scale[f0 + j]; sh[j] = shift[f0 + j]; }

    int dst = gw;
    if (dst >= n) return;
    int s0 = offsets[dst], s1 = offsets[dst + 1];
    float sw = selfw[dst];
    short8 hv = *(const short8*)(h + (size_t)dst * HDIM + f0);

    while (dst < n) {
        int nd = dst + nw;
        int ns0 = 0, ns1 = 0; float nsw = 0.f; short8 nhv = {};
        if (nd < n) {
            ns0 = offsets[nd]; ns1 = offsets[nd + 1]; nsw = selfw[nd];
            nhv = *(const short8*)(h + (size_t)nd * HDIM + f0);
        }

        float acc[8], t[8];
        bnlk8(hv, sc, sh, t);
#pragma unroll
        for (int j = 0; j < 8; j++) acc[j] = sw * t[j];

        int p = s0;
        for (; p + 3 < s1; p += 4) {
            EdgeRec e0 = er[p], e1 = er[p + 1], e2 = er[p + 2], e3 = er[p + 3];
            short8 v0 = *(const short8*)(h + (size_t)e0.src * HDIM + f0);
            short8 v1 = *(const short8*)(h + (size_t)e1.src * HDIM + f0);
            short8 v2 = *(const short8*)(h + (size_t)e2.src * HDIM + f0);
            short8 v3 = *(const short8*)(h + (size_t)e3.src * HDIM + f0);
            float t0[8], t1[8], t2[8], t3[8];
            bnlk8(v0, sc, sh, t0); bnlk8(v1, sc, sh, t1);
            bnlk8(v2, sc, sh, t2); bnlk8(v3, sc, sh, t3);
#pragma unroll
            for (int j = 0; j < 8; j++)
                acc[j] += e0.nm * t0[j] + e1.nm * t1[j] + e2.nm * t2[j] + e3.nm * t3[j];
        }
        int rem = s1 - p;
        if (rem > 0) {
            EdgeRec e0 = er[p], e1 = e0, e2 = e0;
            if (rem > 1) e1 = er[p + 1];
            if (rem > 2) e2 = er[p + 2];
            short8 v0 = *(const short8*)(h + (size_t)e0.src * HDIM + f0);
            short8 v1 = {}, v2 = {};
            if (rem > 1) v1 = *(const short8*)(h + (size_t)e1.src * HDIM + f0);
            if (rem > 2) v2 = *(const short8*)(h + (size_t)e2.src * HDIM + f0);
            float t0[8];
            bnlk8(v0, sc, sh, t0);
#pragma unroll
            for (int j = 0; j < 8; j++) acc[j] += e0.nm * t0[j];
            if (rem > 1) {
                float t1[8]; bnlk8(v1, sc, sh, t1);
#pragma unroll
                for (int j = 0; j < 8; j++) acc[j] += e1.nm * t1[j];
            }
            if (rem > 2) {
                float t2[8]; bnlk8(v2, sc, sh, t2);
#pragma unroll
                for (int j = 0; j < 8; j++) acc[j] += e2.nm * t2[j];
            }
        }

        short8 o;
#pragma unroll
        for (int j = 0; j < 8; j++) ((bf16*)&o)[j] = __float2bfloat16(acc[j]);
        *(short8*)(y + (size_t)dst * HDIM + f0) = o;

        dst = nd; s0 = ns0; s1 = ns1; sw = nsw; hv = nhv;
    }
}

// ------ BN coeffs from striped partials; re-zeros gpart for the next layer --------
__global__ void bn_final(float* __restrict__ gpart,
                         const void* __restrict__ gamma, const void* __restrict__ beta,
                         float* __restrict__ scale, float* __restrict__ shift,
                         float invN, const int* __restrict__ flags)
{
    int f = threadIdx.x;
    float s = 0.f, q = 0.f;
#pragma unroll
    for (int k = 0; k < STRIPES; k++) {
        s += gpart[(size_t)k * 2 * HDIM + f];
        q += gpart[(size_t)k * 2 * HDIM + HDIM + f];
        gpart[(size_t)k * 2 * HDIM + f] = 0.f;
        gpart[(size_t)k * 2 * HDIM + HDIM + f] = 0.f;
    }
    float g = flags[1] ? ((const float*)gamma)[f]
                       : __bfloat162float(((const bf16*)gamma)[f]);
    float b = flags[1] ? ((const float*)beta)[f]
                       : __bfloat162float(((const bf16*)beta)[f]);
    float mu = s * invN;
    float var = fmaxf(q * invN - mu * mu, 0.f);
    float inv = rsqrtf(var + BN_EPS);
    float sc = g * inv;
    scale[f] = sc;
    shift[f] = b - mu * sc;
}

// ---- pooling: wave per graph, 16B/lane loads, fused BN+leaky (monotone) ----------
__global__ __launch_bounds__(256) void pool_fused(
    const bf16* __restrict__ y, const int* __restrict__ batch,
    const float* __restrict__ scale, const float* __restrict__ shift,
    bf16* __restrict__ pooled, int n, int G)
{
    int wave = threadIdx.x >> 6, lane = threadIdx.x & 63;
    int g = blockIdx.x * 4 + wave;
    if (g >= G) return;
    int f0 = lane * 8;

    int lo = 0, hi = n;
    while (lo < hi) { int mid = (lo + hi) >> 1; if (batch[mid] < g) lo = mid + 1; else hi = mid; }
    int s = lo;
    hi = n;
    while (lo < hi) { int mid = (lo + hi) >> 1; if (batch[mid] <= g) lo = mid + 1; else hi = mid; }
    int e = lo;

    float mx[8], mn[8];
#pragma unroll
    for (int j = 0; j < 8; j++) { mx[j] = -3.0e38f; mn[j] = 3.0e38f; }

    int rr = s;
    for (; rr + 1 < e; rr += 2) {
        short8 v0 = *(const short8*)(y + (size_t)rr * HDIM + f0);
        short8 v1 = *(const short8*)(y + (size_t)(rr + 1) * HDIM + f0);
#pragma unroll
        for (int j = 0; j < 8; j++) {
            float a = bf2f(v0[j]), b = bf2f(v1[j]);
            mx[j] = fmaxf(mx[j], fmaxf(a, b));
            mn[j] = fminf(mn[j], fminf(a, b));
        }
    }
    if (rr < e) {
        short8 v0 = *(const short8*)(y + (size_t)rr * HDIM + f0);
#pragma unroll
        for (int j = 0; j < 8; j++) {
            float a = bf2f(v0[j]);
            mx[j] = fmaxf(mx[j], a);
            mn[j] = fminf(mn[j], a);
        }
    }

    short8 o;
#pragma unroll
    for (int j = 0; j < 8; j++) {
        float outv = 0.f;
        if (s < e) {
            float sc = scale[f0 + j];
            float t = sc * (sc >= 0.f ? mx[j] : mn[j]) + shift[f0 + j];
            outv = t > 0.f ? t : SLOPE * t;
        }
        ((bf16*)&o)[j] = __float2bfloat16(outv);
    }
    *(short8*)(pooled + (size_t)g * HDIM + f0) = o;
}

// ---------------- orchestration --------------------------------------------------
extern "C" void kernel_launch(void* const* d_in, const int* in_sizes, int n_in,
                              void* d_out, int out_size, void* d_ws, size_t ws_size,
                              hipStream_t stream)
{
    const void* x     = d_in[0];
    const int*  ei    = (const int*)d_in[1];
    const int*  batch = (const int*)d_in[2];
    // d_in[4]=b1, d_in[8]=b2 cancel in training-mode BatchNorm — unused.

    const int N   = in_sizes[2];
    const int E   = in_sizes[1] / 2;
    const int DIN = 128;
    const int OUT = 256;
    const int G   = out_size / OUT;
    const int Mp  = (N + 127) & ~127;
    const int MB  = Mp / 128;
    const int MB8 = (MB + 7) & ~7;

    // workspace carve — ~238 MB
    char* p = (char*)d_ws;
    bf16* B1     = (bf16*)p;  p += (size_t)Mp * HDIM * sizeof(bf16);
    bf16* B2     = (bf16*)p;  p += (size_t)Mp * HDIM * sizeof(bf16);
    bf16* Q      = (bf16*)p;  p += (size_t)Mp * DIN * sizeof(bf16);
    bf16* W1T    = (bf16*)p;  p += (size_t)HDIM * DIN * sizeof(bf16);
    bf16* W2T    = (bf16*)p;  p += (size_t)HDIM * HDIM * sizeof(bf16);
    bf16* WfT    = (bf16*)p;  p += (size_t)OUT * HDIM * sizeof(bf16);
    bf16* bfbf   = (bf16*)p;  p += 512 * sizeof(bf16);
    int* ei32    = (int*)p;   p += (size_t)2 * E * sizeof(int);
    int* batch32 = (int*)p;   p += (size_t)N * sizeof(int);
    float* dinv  = (float*)p; p += (size_t)N * sizeof(float);
    float* selfw = (float*)p; p += (size_t)N * sizeof(float);
    int* offsets = (int*)p;   p += (size_t)(N + 4) * sizeof(int);
    int* cursor  = (int*)p;   p += (size_t)N * sizeof(int);
    EdgeRec* er  = (EdgeRec*)p; p += (size_t)E * sizeof(EdgeRec);
    int* bsum    = (int*)p;   p += 1024 * sizeof(int);
    float* gpart = (float*)p; p += (size_t)STRIPES * 2 * HDIM * sizeof(float);
    float* sc1   = (float*)p; p += HDIM * sizeof(float);
    float* sh1   = (float*)p; p += HDIM * sizeof(float);
    float* sc2   = (float*)p; p += HDIM * sizeof(float);
    float* sh2   = (float*)p; p += HDIM * sizeof(float);
    int* flags   = (int*)p;   p += 4 * sizeof(int);

    // ---- detection (+gpart zero) + fused conversions + degree count ----
    detect_types<<<1, 256, 0, stream>>>(ei, (const unsigned*)x, flags, gpart);
    hipMemsetAsync(cursor, 0, (size_t)N * sizeof(int), stream);
    conv_all_idx<<<(2 * E + N + 255) / 256, 256, 0, stream>>>(
        ei, batch, ei32, batch32, cursor, 2 * E, N, flags);
    wt_conv_all<<<(128 * 512 + 512 * 512 + 512 * 256 + 256 + 255) / 256, 256, 0, stream>>>(
        d_in[3], d_in[7], d_in[11], d_in[12], W1T, W2T, WfT, bfbf, flags);

    const int* rows = ei32;
    const int* cols = ei32 + E;

    // ---- CSR + degrees (fused into scan_part) + packed edge records ----
    int nb = (N + 511) / 512;
    scan_part<<<nb, 256, 0, stream>>>(cursor, offsets, bsum, dinv, selfw, N);
    scan_tops<<<1, 1024, 0, stream>>>(bsum, nb);
    scan_add<<<nb, 256, 0, stream>>>(offsets, bsum, N, E);
    hipMemsetAsync(cursor, 0, (size_t)N * sizeof(int), stream);
    scatter_edges<<<(E + 255) / 256, 256, 0, stream>>>(rows, cols, offsets, cursor,
                                                       dinv, er, E);

    int gemm_blocks = MB8 * (HDIM / 128);

    // ---- layer 1: aggregate x (agg is linear), GEMM w/ fused stats ----
    agg_csr_din<<<2048, 256, 0, stream>>>(x, offsets, er, selfw, Q, N, flags);
    gemm_m97<true><<<gemm_blocks, 256, 0, stream>>>(
        Q, W1T, B2, nullptr, N, DIN, HDIM, nullptr, gpart, MB);
    bn_final<<<1, HDIM, 0, stream>>>(gpart, d_in[5], d_in[6], sc1, sh1, 1.0f / N, flags);

    // ---- layer 2: aggregate RAW conv1 output w/ fused BN+leaky, GEMM w/ stats ----
    agg_csr_bn<<<2048, 256, 0, stream>>>(B2, offsets, er, selfw, sc1, sh1, B1, N);
    gemm_m97<true><<<gemm_blocks, 256, 0, stream>>>(
        B1, W2T, B2, nullptr, N, HDIM, HDIM, nullptr, gpart, MB);
    bn_final<<<1, HDIM, 0, stream>>>(gpart, d_in[9], d_in[10], sc2, sh2, 1.0f / N, flags);

    // ---- pool (wave/graph, fused BN+leaky) + head GEMM ----
    pool_fused<<<(G + 3) / 4, 256, 0, stream>>>(B2, batch32, sc2, sh2, Q, N, G);
    gemm_m97<false><<<(G / 128) * (OUT / 128), 256, 0, stream>>>(
        Q, WfT, d_out, bfbf, G, HDIM, OUT, flags + 1, nullptr, G / 128);
}

// Round 10
// 417.099 us; speedup vs baseline: 1.0565x; 1.0358x over previous
//
#include <hip/hip_runtime.h>
#include <hip/hip_bf16.h>

typedef __hip_bfloat16 bf16;
typedef __attribute__((ext_vector_type(8))) short short8;
typedef __attribute__((ext_vector_type(4))) float f32x4;

#define HDIM 512
#define SLOPE 0.01f
#define BN_EPS 1e-5f
#define STRIPES 8

__device__ inline float bf2f(short s) {
    unsigned u = ((unsigned)(unsigned short)s) << 16;
    return __builtin_bit_cast(float, u);
}
__device__ inline unsigned short f2bfbits(float v) {
    bf16 h = __float2bfloat16(v);
    return (unsigned short)__builtin_bit_cast(short, h);
}

// float atomic max/min via int ordering trick (works for LDS and global, all signs)
__device__ inline void atomicMaxF(float* a, float v) {
    if (v >= 0.f) atomicMax((int*)a, __float_as_int(v));
    else          atomicMin((unsigned int*)a, __float_as_uint(v));
}
__device__ inline void atomicMinF(float* a, float v) {
    if (v >= 0.f) atomicMin((int*)a, __float_as_int(v));
    else          atomicMax((unsigned int*)a, __float_as_uint(v));
}

// packed edge record: src node + precomputed norm (single 8B load in gather loop)
struct EdgeRec { int src; float nm; };

// ---------------- dtype detection + gpart zero-init ----------------
__global__ void detect_types(const int* __restrict__ ei, const unsigned* __restrict__ xw,
                             int* __restrict__ flags, float* __restrict__ gpart) {
    __shared__ int nzhi, okbf;
    if (threadIdx.x == 0) { nzhi = 0; okbf = 0; }
    __syncthreads();
    int lo = 0, ok = 0;
    for (int i = threadIdx.x; i < 2048; i += 256)
        if (ei[2 * i + 1] != 0) lo++;
    for (int i = threadIdx.x; i < 1024; i += 256) {
        unsigned w = (xw[i] & 0xFFFFu) << 16;
        float av = fabsf(__builtin_bit_cast(float, w));
        if (av > 0.0009f && av < 64.0f) ok++;
    }
    for (int i = threadIdx.x; i < STRIPES * 2 * HDIM; i += 256) gpart[i] = 0.f;
    if (lo) atomicAdd(&nzhi, lo);
    if (ok) atomicAdd(&okbf, ok);
    __syncthreads();
    if (threadIdx.x == 0) {
        flags[0] = (nzhi == 0) ? 1 : 0;
        flags[1] = (okbf < 512) ? 1 : 0;
    }
}

// merged: ei/batch int32 conversion + in-degree count + weight transpose + bias
__global__ void conv_wt_all(const int* __restrict__ ei, const int* __restrict__ batch,
                            int* __restrict__ ei32, int* __restrict__ batch32,
                            int* __restrict__ cnt, int e2, int n,
                            const void* __restrict__ W1, const void* __restrict__ W2,
                            const void* __restrict__ Wf, const void* __restrict__ bf_,
                            bf16* __restrict__ W1T, bf16* __restrict__ W2T,
                            bf16* __restrict__ WfT, bf16* __restrict__ bfbf,
                            const int* __restrict__ flags) {
    const int S1 = 128 * 512, S2 = 512 * 512, S3 = 512 * 256;
    int i = blockIdx.x * 256 + threadIdx.x;
    int i64 = flags[0];
    bool f32 = flags[1] != 0;
    if (i < e2) {
        int v = i64 ? (int)((const long long*)ei)[i] : ei[i];
        ei32[i] = v;
        if (i >= e2 / 2) atomicAdd(&cnt[v], 1);   // cols half
    } else if (i < e2 + n) {
        int j = i - e2;
        batch32[j] = i64 ? (int)((const long long*)batch)[j] : batch[j];
    } else {
        int idx = i - e2 - n;
        if (idx < S1) {
            int nn = idx / 128, k = idx - nn * 128;   // K=128, Nn=512
            float v = f32 ? ((const float*)W1)[(size_t)k * 512 + nn]
                          : __bfloat162float(((const bf16*)W1)[(size_t)k * 512 + nn]);
            W1T[idx] = __float2bfloat16(v);
        } else if (idx < S1 + S2) {
            int t = idx - S1;
            int nn = t / 512, k = t - nn * 512;       // K=512, Nn=512
            float v = f32 ? ((const float*)W2)[(size_t)k * 512 + nn]
                          : __bfloat162float(((const bf16*)W2)[(size_t)k * 512 + nn]);
            W2T[t] = __float2bfloat16(v);
        } else if (idx < S1 + S2 + S3) {
            int t = idx - S1 - S2;
            int nn = t / 512, k = t - nn * 512;       // K=512, Nn=256
            float v = f32 ? ((const float*)Wf)[(size_t)k * 256 + nn]
                          : __bfloat162float(((const bf16*)Wf)[(size_t)k * 256 + nn]);
            WfT[t] = __float2bfloat16(v);
        } else if (idx < S1 + S2 + S3 + 256) {
            int t = idx - S1 - S2 - S3;
            float v = f32 ? ((const float*)bf_)[t]
                          : __bfloat162float(((const bf16*)bf_)[t]);
            bfbf[t] = __float2bfloat16(v);
        }
    }
}

// ---------------- parallel exclusive scan (3 kernels, 512 elems/block) -----------
// scan_part also finalizes degrees (dinv/selfw) from the same counts it loads.
__global__ __launch_bounds__(256) void scan_part(
    const int* __restrict__ counts, int* __restrict__ offsets,
    int* __restrict__ bsum, float* __restrict__ dinv, float* __restrict__ selfw,
    int n)
{
    __shared__ int s[512];
    int b = blockIdx.x;
    int base = b * 512;
    int t = threadIdx.x;
    int c0 = (base + t       < n) ? counts[base + t]       : 0;
    int c1 = (base + t + 256 < n) ? counts[base + t + 256] : 0;
    s[t] = c0; s[t + 256] = c1;
    if (base + t < n) {
        float d = (float)c0 + 2.0f;
        dinv[base + t] = rsqrtf(d);
        selfw[base + t] = 2.0f / d;
    }
    if (base + t + 256 < n) {
        float d = (float)c1 + 2.0f;
        dinv[base + t + 256] = rsqrtf(d);
        selfw[base + t + 256] = 2.0f / d;
    }

    int offset = 1;
    for (int d = 256; d > 0; d >>= 1) {
        __syncthreads();
        if (t < d) {
            int ai = offset * (2 * t + 1) - 1;
            int bi = offset * (2 * t + 2) - 1;
            s[bi] += s[ai];
        }
        offset <<= 1;
    }
    __syncthreads();
    if (t == 0) { bsum[b] = s[511]; s[511] = 0; }
    for (int d = 1; d < 512; d <<= 1) {
        offset >>= 1;
        __syncthreads();
        if (t < d) {
            int ai = offset * (2 * t + 1) - 1;
            int bi = offset * (2 * t + 2) - 1;
            int tmp = s[ai]; s[ai] = s[bi]; s[bi] += tmp;
        }
    }
    __syncthreads();
    if (base + t < n)       offsets[base + t]       = s[t];
    if (base + t + 256 < n) offsets[base + t + 256] = s[t + 256];
}

__global__ __launch_bounds__(1024) void scan_tops(int* __restrict__ bsum, int nb) {
    __shared__ int s[1024];
    int t = threadIdx.x;
    s[t] = (t < nb) ? bsum[t] : 0;
    __syncthreads();
    for (int off = 1; off < 1024; off <<= 1) {
        int v = (t >= off) ? s[t - off] : 0;
        __syncthreads();
        s[t] += v;
        __syncthreads();
    }
    if (t < nb) bsum[t] = (t == 0) ? 0 : s[t - 1];   // exclusive
}

// scan_add dual-writes cursor = offsets so scatter needs no memset + no re-read
__global__ __launch_bounds__(256) void scan_add(
    int* __restrict__ offsets, const int* __restrict__ bsum,
    int* __restrict__ cursor, int n, int e)
{
    int b = blockIdx.x;
    int base = b * 512;
    int add = bsum[b];
    int t = threadIdx.x;
    if (base + t < n) {
        int v = offsets[base + t] + add;
        offsets[base + t] = v; cursor[base + t] = v;
    }
    if (base + t + 256 < n) {
        int v = offsets[base + t + 256] + add;
        offsets[base + t + 256] = v; cursor[base + t + 256] = v;
    }
    if (b == 0 && t == 0) offsets[n] = e;
}

// scatter edges into CSR order; cursor pre-seeded with start offsets
__global__ void scatter_edges(const int* __restrict__ rows, const int* __restrict__ cols,
                              int* __restrict__ cursor, const float* __restrict__ dinv,
                              EdgeRec* __restrict__ er, int e)
{
    int i = blockIdx.x * blockDim.x + threadIdx.x;
    if (i < e) {
        int d = cols[i];
        int r = rows[i];
        int pos = atomicAdd(&cursor[d], 1);
        EdgeRec rec;
        rec.src = r;
        rec.nm = dinv[d] * dinv[r];
        er[pos] = rec;
    }
}

// ---- pooled slot init: [s0max | s0min | s1max | s1min], each gn floats ----------
__global__ __launch_bounds__(256) void pool_init2(float* __restrict__ pS, int total, int gn) {
    int i = blockIdx.x * 256 + threadIdx.x;
    if (i < total) pS[i] = ((i / gn) & 1) ? 3.0e38f : -3.0e38f;
}

// ---- pooled finalize: merge slots, BN+leaky monotone-select, empty->0 -----------
__global__ __launch_bounds__(256) void pool_fin2(
    const float* __restrict__ pS, const float* __restrict__ scale,
    const float* __restrict__ shift, bf16* __restrict__ outQ, int gn)
{
    int i = blockIdx.x * 256 + threadIdx.x;
    if (i >= gn) return;
    int c = i & (HDIM - 1);
    float vmax = fmaxf(pS[i], pS[2 * (size_t)gn + i]);
    float vmin = fminf(pS[(size_t)gn + i], pS[3 * (size_t)gn + i]);
    float outv = 0.f;
    if (vmax > -2.9e38f) {
        float s = scale[c];
        float t = s * (s >= 0.f ? vmax : vmin) + shift[c];
        outv = t > 0.f ? t : SLOPE * t;
    }
    outQ[i] = __float2bfloat16(outv);
}

// ------ m97-style GEMM, BK=32, natural grid order, LDS XOR-swizzle ----------------
// T4 counted-vmcnt 2-deep pipeline (verified, round-7/9). Natural grid mapping is
// already XCD-optimal (round-8 lesson: explicit remap -8 µs). POOL epilogue:
// no C-write; per-block run-length -> LDS atomics (32KB reuse) -> plain-store
// per-graph partials to home slot0, boundary graph via global atomics to slot1
// (~1 graph/block -> ~800K atomics total, vs round-2's 19M storm).
#define GEMM_STAGE(boff, kk)                                                             \
    {                                                                                    \
        _Pragma("unroll")                                                                \
        for (int i_ = 0; i_ < 2; i_++) {                                                 \
            int c_ = wave * 2 + i_;                                                      \
            const bf16* ga_ = A  + (size_t)(m0 + c_ * 16 + lrow) * K + (kk) + lcol;      \
            const bf16* gb_ = BT + (size_t)(n0 + c_ * 16 + lrow) * K + (kk) + lcol;      \
            __builtin_amdgcn_global_load_lds(                                            \
                (const __attribute__((address_space(1))) unsigned*)ga_,                  \
                (__attribute__((address_space(3))) unsigned*)(smem + (boff) + c_ * 512), \
                16, 0, 0);                                                               \
            __builtin_amdgcn_global_load_lds(                                            \
                (const __attribute__((address_space(1))) unsigned*)gb_,                  \
                (__attribute__((address_space(3))) unsigned*)(smem + 8192 + (boff) + c_ * 512), \
                16, 0, 0);                                                               \
        }                                                                                \
    }

#define GEMM_COMPUTE(boff)                                                               \
    {                                                                                    \
        short8 a[4], b[4];                                                               \
        _Pragma("unroll")                                                                \
        for (int mi2 = 0; mi2 < 4; mi2++)                                                \
            a[mi2] = *(const short8*)&smem[(boff) + (wm + mi2 * 16 + r) * 32 + aoff];    \
        _Pragma("unroll")                                                                \
        for (int ni = 0; ni < 4; ni++)                                                   \
            b[ni] = *(const short8*)&smem[8192 + (boff) + (wn + ni * 16 + r) * 32 + aoff]; \
        _Pragma("unroll")                                                                \
        for (int mi2 = 0; mi2 < 4; mi2++)                                                \
            _Pragma("unroll")                                                            \
            for (int ni = 0; ni < 4; ni++)                                               \
                acc[mi2][ni] = __builtin_amdgcn_mfma_f32_16x16x32_bf16(                  \
                    a[mi2], b[ni], acc[mi2][ni], 0, 0, 0);                               \
    }

template<bool STATS, bool POOL>
__global__ __launch_bounds__(256, 4) void gemm_m97(
    const bf16* __restrict__ A, const bf16* __restrict__ BT,
    void* __restrict__ C, const bf16* __restrict__ bias,
    int M, int K, int N, const int* __restrict__ cf32,
    float* __restrict__ gpart, int MB,
    const int* __restrict__ batchp, float* __restrict__ pS, int gn_total)
{
    // layout: [0,4096)=As buf0, [4096,8192)=As buf1, [8192,12288)=Bs buf0,
    //         [12288,16384)=Bs buf1 — 32 KB, reused as C tile / pool partials
    __shared__ bf16 smem[16384];

    int NBN = N >> 7;
    int id = blockIdx.x;
    int grp = id / (8 * NBN);
    int loc = id - grp * 8 * NBN;
    int mi = loc & 7;
    int nblk = loc >> 3;
    int mblk = grp * 8 + mi;
    if (mblk >= MB) return;

    int tid = threadIdx.x;
    int wave = tid >> 6, lane = tid & 63, q = lane >> 4, r = lane & 15;
    int wm = (wave >> 1) * 64, wn = (wave & 1) * 64;
    int m0 = mblk * 128, n0 = nblk * 128;
    bool c32 = cf32 && *cf32;

    int lrow = lane >> 2;
    int lcol = (((lane & 3) ^ ((lane >> 3) & 3)) * 8);   // XOR-swizzled source chunk
    int aoff = (q ^ ((r >> 1) & 3)) * 8;                 // fragment-read swizzle

    f32x4 acc[4][4];
#pragma unroll
    for (int mi2 = 0; mi2 < 4; mi2++)
#pragma unroll
        for (int ni = 0; ni < 4; ni++)
            acc[mi2][ni] = {0.f, 0.f, 0.f, 0.f};

    const int nK = K >> 5;

    // prologue: fill buffer 0 (4 loads in flight; first loop iter waits via vmcnt(4))
    GEMM_STAGE(0, 0);

    int cur = 0;
    for (int t = 1; t < nK; ++t) {
        GEMM_STAGE(cur ^ 4096, t * 32);   // issue next tile (8 outstanding/wave)
        asm volatile("s_waitcnt vmcnt(4)" ::: "memory");   // prev tile landed
        __builtin_amdgcn_sched_barrier(0);
        __builtin_amdgcn_s_barrier();     // all waves: cur buffer fully resident
        __builtin_amdgcn_sched_barrier(0);
        GEMM_COMPUTE(cur);                // ds_read + 16 MFMA (next loads in flight)
        asm volatile("s_waitcnt lgkmcnt(0)" ::: "memory"); // my ds_reads done
        __builtin_amdgcn_sched_barrier(0);
        __builtin_amdgcn_s_barrier();     // all waves done reading cur -> reusable
        __builtin_amdgcn_sched_barrier(0);
        cur ^= 4096;
    }
    asm volatile("s_waitcnt vmcnt(0)" ::: "memory");       // last tile landed
    __builtin_amdgcn_sched_barrier(0);
    __builtin_amdgcn_s_barrier();
    __builtin_amdgcn_sched_barrier(0);
    GEMM_COMPUTE(cur);                    // last tile, no prefetch

    if constexpr (!POOL) {
        if (!c32) {
            // ---- vectorized epilogue: stage C tile in LDS, write 16B/lane ----
            __syncthreads();             // full drain: all waves done with As/Bs
#pragma unroll
            for (int mi2 = 0; mi2 < 4; mi2++) {
#pragma unroll
                for (int ni = 0; ni < 4; ni++) {
                    int lc = wn + ni * 16 + r;
                    float bv = bias ? __bfloat162float(bias[n0 + lc]) : 0.f;
#pragma unroll
                    for (int reg = 0; reg < 4; reg++) {
                        int lr = wm + mi2 * 16 + q * 4 + reg;
                        int bo = ((lr << 8) + (lc << 1)) ^ (q << 5);  // q-XOR
                        *(bf16*)((char*)smem + bo) = __float2bfloat16(acc[mi2][ni][reg] + bv);
                    }
                }
            }
            __syncthreads();
#pragma unroll
            for (int pss = 0; pss < 8; pss++) {
                int off = pss * 4096 + tid * 16;
                int row = off >> 8;
                int cb = off & 255;
                int rb = cb ^ (((row >> 2) & 3) << 5);   // un-swizzle
                f32x4 v = *(const f32x4*)((const char*)smem + (row << 8) + rb);
                int gm = m0 + row;
                if (gm < M)
                    *(f32x4*)((char*)C + (((size_t)gm * N + n0) << 1) + cb) = v;
            }
        } else {
            // f32 output path (head GEMM with f32 inputs): scalar stores
#pragma unroll
            for (int mi2 = 0; mi2 < 4; mi2++) {
#pragma unroll
                for (int ni = 0; ni < 4; ni++) {
                    int gn = n0 + wn + ni * 16 + r;
                    float bv = bias ? __bfloat162float(bias[gn]) : 0.f;
#pragma unroll
                    for (int reg = 0; reg < 4; reg++) {
                        int gm = m0 + wm + mi2 * 16 + q * 4 + reg;
                        if (gm < M)
                            ((float*)C)[(size_t)gm * N + gn] = acc[mi2][ni][reg] + bv;
                    }
                }
            }
        }
    }

    if constexpr (POOL) {
        // ---- fused max/min pooling partials (no C-write) ----
        int batchv[16];
#pragma unroll
        for (int mi2 = 0; mi2 < 4; mi2++)
#pragma unroll
            for (int reg = 0; reg < 4; reg++) {
                int gm = m0 + wm + mi2 * 16 + q * 4 + reg;
                batchv[mi2 * 4 + reg] = (gm < M) ? batchp[gm] : -1;
            }
        int gfirst = batchp[m0];
        int lastrow = (m0 + 127 < M) ? (m0 + 127) : (M - 1);
        int glast = batchp[lastrow];
        int ng = glast - gfirst + 1;
        bool home0 = (m0 == 0) || (batchp[m0 - 1] < gfirst);
        float* part  = (float*)smem;
        float* s0max = pS;
        float* s0min = pS + (size_t)gn_total;
        float* s1max = pS + 2 * (size_t)gn_total;
        float* s1min = pS + 3 * (size_t)gn_total;
        __syncthreads();   // all waves done with As/Bs before smem reuse
        for (int gbase = 0; gbase < ng; gbase += 32) {
            int nwin = ng - gbase; if (nwin > 32) nwin = 32;
            for (int i = tid; i < nwin * 256; i += 256)
                part[i] = (i & 1) ? 3.0e38f : -3.0e38f;
            __syncthreads();
#pragma unroll
            for (int ni = 0; ni < 4; ni++) {
                int lc = wn + ni * 16 + r;
                float cmax = 0.f, cmin = 0.f;
                int curg = -1;
#pragma unroll
                for (int t2 = 0; t2 < 16; t2++) {
                    int g2 = batchv[t2];
                    float v = acc[t2 >> 2][ni][t2 & 3];
                    if (g2 >= 0) {
                        if (g2 != curg) {
                            if (curg >= 0) {
                                int gi = curg - gfirst - gbase;
                                if (gi >= 0 && gi < nwin) {
                                    atomicMaxF(&part[(gi * 128 + lc) * 2], cmax);
                                    atomicMinF(&part[(gi * 128 + lc) * 2 + 1], cmin);
                                }
                            }
                            curg = g2; cmax = v; cmin = v;
                        } else {
                            cmax = fmaxf(cmax, v); cmin = fminf(cmin, v);
                        }
                    }
                }
                if (curg >= 0) {
                    int gi = curg - gfirst - gbase;
                    if (gi >= 0 && gi < nwin) {
                        atomicMaxF(&part[(gi * 128 + lc) * 2], cmax);
                        atomicMinF(&part[(gi * 128 + lc) * 2 + 1], cmin);
                    }
                }
            }
            __syncthreads();
            for (int i = tid; i < nwin * 256; i += 256) {
                int cell = i >> 1;
                int gi = cell >> 7, col = cell & 127;
                int g2 = gfirst + gbase + gi;
                float v = part[i];
                size_t gidx = (size_t)g2 * N + n0 + col;
                bool nh = (g2 == gfirst) && !home0;   // boundary graph -> slot1
                if (i & 1) {
                    if (nh) atomicMinF(&s1min[gidx], v); else s0min[gidx] = v;
                } else {
                    if (nh) atomicMaxF(&s1max[gidx], v); else s0max[gidx] = v;
                }
            }
            __syncthreads();
        }
    }

    if constexpr (STATS) {
        float* base = gpart + (size_t)(mblk & (STRIPES - 1)) * 2 * HDIM;
#pragma unroll
        for (int ni = 0; ni < 4; ni++) {
            float cs = 0.f, cq = 0.f;
#pragma unroll
            for (int mi2 = 0; mi2 < 4; mi2++)
#pragma unroll
                for (int reg = 0; reg < 4; reg++) {
                    int gm = m0 + wm + mi2 * 16 + q * 4 + reg;
                    if (gm < M) {
                        float v = acc[mi2][ni][reg];
                        cs += v; cq += v * v;
                    }
                }
            // reduce over q (lanes r, r+16, r+32, r+48 share column wn+ni*16+r)
            cs += __shfl_xor(cs, 16, 64);
            cs += __shfl_xor(cs, 32, 64);
            cq += __shfl_xor(cq, 16, 64);
            cq += __shfl_xor(cq, 32, 64);
            if (q == 0) {
                int c = n0 + wn + ni * 16 + r;
                atomicAdd(&base[c], cs);
                atomicAdd(&base[HDIM + c], cq);
            }
        }
    }
}

// ----- persistent CSR aggregation, 128-dim input -----------------------------------
#define AGG_DIN_BODY(LOADV)                                                            \
    int dst = gw;                                                                      \
    if (dst < n) {                                                                     \
        int s0 = offsets[dst], s1 = offsets[dst + 1];                                  \
        float sw = selfw[dst];                                                         \
        float h0, h1; LOADV(dst, h0, h1);                                              \
        while (dst < n) {                                                              \
            int nd = dst + nw;                                                         \
            int ns0 = 0, ns1 = 0; float nsw = 0.f, nh0 = 0.f, nh1 = 0.f;               \
            if (nd < n) {                                                              \
                ns0 = offsets[nd]; ns1 = offsets[nd + 1]; nsw = selfw[nd];             \
                LOADV(nd, nh0, nh1);                                                   \
            }                                                                          \
            float a0 = sw * h0, a1 = sw * h1;                                          \
            int p = s0;                                                                \
            for (; p + 3 < s1; p += 4) {                                               \
                EdgeRec e0 = er[p], e1 = er[p + 1], e2 = er[p + 2], e3 = er[p + 3];    \
                float x0, y0, x1, y1, x2, y2, x3, y3;                                  \
                LOADV(e0.src, x0, y0); LOADV(e1.src, x1, y1);                          \
                LOADV(e2.src, x2, y2); LOADV(e3.src, x3, y3);                          \
                a0 += e0.nm * x0 + e1.nm * x1 + e2.nm * x2 + e3.nm * x3;               \
                a1 += e0.nm * y0 + e1.nm * y1 + e2.nm * y2 + e3.nm * y3;               \
            }                                                                          \
            int rem = s1 - p;                                                          \
            if (rem > 0) {                                                             \
                EdgeRec e0 = er[p], e1 = e0, e2 = e0;                                  \
                if (rem > 1) e1 = er[p + 1];                                           \
                if (rem > 2) e2 = er[p + 2];                                           \
                float x0, y0, x1 = 0.f, y1 = 0.f, x2 = 0.f, y2 = 0.f;                  \
                LOADV(e0.src, x0, y0);                                                 \
                if (rem > 1) LOADV(e1.src, x1, y1);                                    \
                if (rem > 2) LOADV(e2.src, x2, y2);                                    \
                a0 += e0.nm * x0; a1 += e0.nm * y0;                                    \
                if (rem > 1) { a0 += e1.nm * x1; a1 += e1.nm * y1; }                   \
                if (rem > 2) { a0 += e2.nm * x2; a1 += e2.nm * y2; }                   \
            }                                                                          \
            ((unsigned*)out)[(size_t)dst * 64 + lane] =                                \
                (unsigned)f2bfbits(a0) | ((unsigned)f2bfbits(a1) << 16);               \
            dst = nd; s0 = ns0; s1 = ns1; sw = nsw; h0 = nh0; h1 = nh1;                \
        }                                                                              \
    }

#define LOADF32(idx, a, b) { float2 v_ = ((const float2*)x)[(size_t)(idx) * 64 + lane]; \
                             a = v_.x; b = v_.y; }
#define LOADBF(idx, a, b)  { unsigned u_ = ((const unsigned*)x)[(size_t)(idx) * 64 + lane]; \
                             a = bf2f((short)(u_ & 0xFFFF)); b = bf2f((short)(u_ >> 16)); }

__global__ __launch_bounds__(256) void agg_csr_din(
    const void* __restrict__ x, const int* __restrict__ offsets,
    const EdgeRec* __restrict__ er, const float* __restrict__ selfw,
    bf16* __restrict__ out, int n, const int* __restrict__ flags)
{
    int wave = threadIdx.x >> 6, lane = threadIdx.x & 63;
    int gw = blockIdx.x * 4 + wave;
    int nw = gridDim.x * 4;
    bool f32 = flags[1] != 0;
    if (f32) { AGG_DIN_BODY(LOADF32) } else { AGG_DIN_BODY(LOADBF) }
}

// -- persistent CSR aggregation (512-dim) with fused BN-affine+leaky ---------------
__device__ inline void bnlk8(const short8& v, const float* sc, const float* sh,
                             float* t) {
#pragma unroll
    for (int j = 0; j < 8; j++) {
        float u = sc[j] * bf2f(v[j]) + sh[j];
        t[j] = u > 0.f ? u : SLOPE * u;
    }
}

__global__ __launch_bounds__(256) void agg_csr_bn(
    const bf16* __restrict__ h, const int* __restrict__ offsets,
    const EdgeRec* __restrict__ er, const float* __restrict__ selfw,
    const float* __restrict__ scale, const float* __restrict__ shift,
    bf16* __restrict__ y, int n)
{
    int wave = threadIdx.x >> 6, lane = threadIdx.x & 63;
    int f0 = lane * 8;
    int gw = blockIdx.x * 4 + wave;
    int nw = gridDim.x * 4;

    float sc[8], sh[8];
#pragma unroll
    for (int j = 0; j < 8; j++) { sc[j] = scale[f0 + j]; sh[j] = shift[f0 + j]; }

    int dst = gw;
    if (dst >= n) return;
    int s0 = offsets[dst], s1 = offsets[dst + 1];
    float sw = selfw[dst];
    short8 hv = *(const short8*)(h + (size_t)dst * HDIM + f0);

    while (dst < n) {
        int nd = dst + nw;
        int ns0 = 0, ns1 = 0; float nsw = 0.f; short8 nhv = {};
        if (nd < n) {
            ns0 = offsets[nd]; ns1 = offsets[nd + 1]; nsw = selfw[nd];
            nhv = *(const short8*)(h + (size_t)nd * HDIM + f0);
        }

        float acc[8], t[8];
        bnlk8(hv, sc, sh, t);
#pragma unroll
        for (int j = 0; j < 8; j++) acc[j] = sw * t[j];

        int p = s0;
        for (; p + 3 < s1; p += 4) {
            EdgeRec e0 = er[p], e1 = er[p + 1], e2 = er[p + 2], e3 = er[p + 3];
            short8 v0 = *(const short8*)(h + (size_t)e0.src * HDIM + f0);
            short8 v1 = *(const short8*)(h + (size_t)e1.src * HDIM + f0);
            short8 v2 = *(const short8*)(h + (size_t)e2.src * HDIM + f0);
            short8 v3 = *(const short8*)(h + (size_t)e3.src * HDIM + f0);
            float t0[8], t1[8], t2[8], t3[8];
            bnlk8(v0, sc, sh, t0); bnlk8(v1, sc, sh, t1);
            bnlk8(v2, sc, sh, t2); bnlk8(v3, sc, sh, t3);
#pragma unroll
            for (int j = 0; j < 8; j++)
                acc[j] += e0.nm * t0[j] + e1.nm * t1[j] + e2.nm * t2[j] + e3.nm * t3[j];
        }
        int rem = s1 - p;
        if (rem > 0) {
            EdgeRec e0 = er[p], e1 = e0, e2 = e0;
            if (rem > 1) e1 = er[p + 1];
            if (rem > 2) e2 = er[p + 2];
            short8 v0 = *(const short8*)(h + (size_t)e0.src * HDIM + f0);
            short8 v1 = {}, v2 = {};
            if (rem > 1) v1 = *(const short8*)(h + (size_t)e1.src * HDIM + f0);
            if (rem > 2) v2 = *(const short8*)(h + (size_t)e2.src * HDIM + f0);
            float t0[8];
            bnlk8(v0, sc, sh, t0);
#pragma unroll
            for (int j = 0; j < 8; j++) acc[j] += e0.nm * t0[j];
            if (rem > 1) {
                float t1[8]; bnlk8(v1, sc, sh, t1);
#pragma unroll
                for (int j = 0; j < 8; j++) acc[j] += e1.nm * t1[j];
            }
            if (rem > 2) {
                float t2[8]; bnlk8(v2, sc, sh, t2);
#pragma unroll
                for (int j = 0; j < 8; j++) acc[j] += e2.nm * t2[j];
            }
        }

        short8 o;
#pragma unroll
        for (int j = 0; j < 8; j++) ((bf16*)&o)[j] = __float2bfloat16(acc[j]);
        *(short8*)(y + (size_t)dst * HDIM + f0) = o;

        dst = nd; s0 = ns0; s1 = ns1; sw = nsw; hv = nhv;
    }
}

// ------ BN coeffs from striped partials; re-zeros gpart for the next layer --------
__global__ void bn_final(float* __restrict__ gpart,
                         const void* __restrict__ gamma, const void* __restrict__ beta,
                         float* __restrict__ scale, float* __restrict__ shift,
                         float invN, const int* __restrict__ flags)
{
    int f = threadIdx.x;
    float s = 0.f, q = 0.f;
#pragma unroll
    for (int k = 0; k < STRIPES; k++) {
        s += gpart[(size_t)k * 2 * HDIM + f];
        q += gpart[(size_t)k * 2 * HDIM + HDIM + f];
        gpart[(size_t)k * 2 * HDIM + f] = 0.f;
        gpart[(size_t)k * 2 * HDIM + HDIM + f] = 0.f;
    }
    float g = flags[1] ? ((const float*)gamma)[f]
                       : __bfloat162float(((const bf16*)gamma)[f]);
    float b = flags[1] ? ((const float*)beta)[f]
                       : __bfloat162float(((const bf16*)beta)[f]);
    float mu = s * invN;
    float var = fmaxf(q * invN - mu * mu, 0.f);
    float inv = rsqrtf(var + BN_EPS);
    float sc = g * inv;
    scale[f] = sc;
    shift[f] = b - mu * sc;
}

// ---------------- orchestration --------------------------------------------------
extern "C" void kernel_launch(void* const* d_in, const int* in_sizes, int n_in,
                              void* d_out, int out_size, void* d_ws, size_t ws_size,
                              hipStream_t stream)
{
    const void* x     = d_in[0];
    const int*  ei    = (const int*)d_in[1];
    const int*  batch = (const int*)d_in[2];
    // d_in[4]=b1, d_in[8]=b2 cancel in training-mode BatchNorm — unused.

    const int N   = in_sizes[2];
    const int E   = in_sizes[1] / 2;
    const int DIN = 128;
    const int OUT = 256;
    const int G   = out_size / OUT;
    const int Mp  = (N + 127) & ~127;
    const int MB  = Mp / 128;
    const int MB8 = (MB + 7) & ~7;

    // workspace carve — ~238 MB
    char* p = (char*)d_ws;
    bf16* B1     = (bf16*)p;  p += (size_t)Mp * HDIM * sizeof(bf16);
    bf16* B2     = (bf16*)p;  p += (size_t)Mp * HDIM * sizeof(bf16);
    bf16* Q      = (bf16*)p;  p += (size_t)Mp * DIN * sizeof(bf16);
    bf16* W1T    = (bf16*)p;  p += (size_t)HDIM * DIN * sizeof(bf16);
    bf16* W2T    = (bf16*)p;  p += (size_t)HDIM * HDIM * sizeof(bf16);
    bf16* WfT    = (bf16*)p;  p += (size_t)OUT * HDIM * sizeof(bf16);
    bf16* bfbf   = (bf16*)p;  p += 512 * sizeof(bf16);
    int* ei32    = (int*)p;   p += (size_t)2 * E * sizeof(int);
    int* batch32 = (int*)p;   p += (size_t)N * sizeof(int);
    float* dinv  = (float*)p; p += (size_t)N * sizeof(float);
    float* selfw = (float*)p; p += (size_t)N * sizeof(float);
    int* offsets = (int*)p;   p += (size_t)(N + 4) * sizeof(int);
    int* cursor  = (int*)p;   p += (size_t)N * sizeof(int);
    EdgeRec* er  = (EdgeRec*)p; p += (size_t)E * sizeof(EdgeRec);
    int* bsum    = (int*)p;   p += 1024 * sizeof(int);
    float* gpart = (float*)p; p += (size_t)STRIPES * 2 * HDIM * sizeof(float);
    float* sc1   = (float*)p; p += HDIM * sizeof(float);
    float* sh1   = (float*)p; p += HDIM * sizeof(float);
    float* sc2   = (float*)p; p += HDIM * sizeof(float);
    float* sh2   = (float*)p; p += HDIM * sizeof(float);
    int* flags   = (int*)p;   p += 4 * sizeof(int);

    // pooled slot buffers live in B2's region (dead after agg_csr_bn reads it):
    // [s0max | s0min | s1max | s1min], each G*HDIM floats = 33.5 MB total
    float* pS = (float*)B2;
    const int GN = G * HDIM;

    // ---- detection (+gpart zero) + fused conversions + degree count ----
    detect_types<<<1, 256, 0, stream>>>(ei, (const unsigned*)x, flags, gpart);
    hipMemsetAsync(cursor, 0, (size_t)N * sizeof(int), stream);
    {
        const int WTOT = 128 * 512 + 512 * 512 + 512 * 256 + 256;
        conv_wt_all<<<(2 * E + N + WTOT + 255) / 256, 256, 0, stream>>>(
            ei, batch, ei32, batch32, cursor, 2 * E, N,
            d_in[3], d_in[7], d_in[11], d_in[12], W1T, W2T, WfT, bfbf, flags);
    }

    const int* rows = ei32;
    const int* cols = ei32 + E;

    // ---- CSR + degrees (fused into scan_part) + packed edge records ----
    int nb = (N + 511) / 512;
    scan_part<<<nb, 256, 0, stream>>>(cursor, offsets, bsum, dinv, selfw, N);
    scan_tops<<<1, 1024, 0, stream>>>(bsum, nb);
    scan_add<<<nb, 256, 0, stream>>>(offsets, bsum, cursor, N, E);
    scatter_edges<<<(E + 255) / 256, 256, 0, stream>>>(rows, cols, cursor, dinv, er, E);

    int gemm_blocks = MB8 * (HDIM / 128);

    // ---- layer 1: aggregate x (agg is linear), GEMM w/ fused stats ----
    agg_csr_din<<<2048, 256, 0, stream>>>(x, offsets, er, selfw, Q, N, flags);
    gemm_m97<true, false><<<gemm_blocks, 256, 0, stream>>>(
        Q, W1T, B2, nullptr, N, DIN, HDIM, nullptr, gpart, MB,
        nullptr, nullptr, 0);
    bn_final<<<1, HDIM, 0, stream>>>(gpart, d_in[5], d_in[6], sc1, sh1, 1.0f / N, flags);

    // ---- layer 2: aggregate conv1 w/ fused BN+leaky, then GEMM with fused stats
    //      AND fused pooling partials (no 102 MB C-write, no 102 MB pool re-read) --
    agg_csr_bn<<<2048, 256, 0, stream>>>(B2, offsets, er, selfw, sc1, sh1, B1, N);
    pool_init2<<<(4 * GN + 255) / 256, 256, 0, stream>>>(pS, 4 * GN, GN);
    gemm_m97<true, true><<<gemm_blocks, 256, 0, stream>>>(
        B1, W2T, nullptr, nullptr, N, HDIM, HDIM, nullptr, gpart, MB,
        batch32, pS, GN);
    bn_final<<<1, HDIM, 0, stream>>>(gpart, d_in[9], d_in[10], sc2, sh2, 1.0f / N, flags);

    // ---- pooled finalize (merge slots, BN+leaky monotone) + head GEMM ----
    pool_fin2<<<(GN + 255) / 256, 256, 0, stream>>>(pS, sc2, sh2, Q, GN);
    gemm_m97<false, false><<<(G / 128) * (OUT / 128), 256, 0, stream>>>(
        Q, WfT, d_out, bfbf, G, HDIM, OUT, flags + 1, nullptr, G / 128,
        nullptr, nullptr, 0);
}

// Round 11
// 414.784 us; speedup vs baseline: 1.0624x; 1.0056x over previous
//
#include <hip/hip_runtime.h>
#include <hip/hip_bf16.h>

typedef __hip_bfloat16 bf16;
typedef __attribute__((ext_vector_type(8))) short short8;
typedef __attribute__((ext_vector_type(4))) float f32x4;

#define HDIM 512
#define SLOPE 0.01f
#define BN_EPS 1e-5f
#define STRIPES 8

__device__ inline float bf2f(short s) {
    unsigned u = ((unsigned)(unsigned short)s) << 16;
    return __builtin_bit_cast(float, u);
}
__device__ inline unsigned short f2bfbits(float v) {
    bf16 h = __float2bfloat16(v);
    return (unsigned short)__builtin_bit_cast(short, h);
}

// float atomic max/min via int ordering trick (works for LDS and global, all signs)
__device__ inline void atomicMaxF(float* a, float v) {
    if (v >= 0.f) atomicMax((int*)a, __float_as_int(v));
    else          atomicMin((unsigned int*)a, __float_as_uint(v));
}
__device__ inline void atomicMinF(float* a, float v) {
    if (v >= 0.f) atomicMin((int*)a, __float_as_int(v));
    else          atomicMax((unsigned int*)a, __float_as_uint(v));
}

// packed edge record: src node + precomputed norm (single 8B load in gather loop)
struct EdgeRec { int src; float nm; };

// ---------------- dtype detection + gpart zero-init ----------------
__global__ void detect_types(const int* __restrict__ ei, const unsigned* __restrict__ xw,
                             int* __restrict__ flags, float* __restrict__ gpart) {
    __shared__ int nzhi, okbf;
    if (threadIdx.x == 0) { nzhi = 0; okbf = 0; }
    __syncthreads();
    int lo = 0, ok = 0;
    for (int i = threadIdx.x; i < 2048; i += 256)
        if (ei[2 * i + 1] != 0) lo++;
    for (int i = threadIdx.x; i < 1024; i += 256) {
        unsigned w = (xw[i] & 0xFFFFu) << 16;
        float av = fabsf(__builtin_bit_cast(float, w));
        if (av > 0.0009f && av < 64.0f) ok++;
    }
    for (int i = threadIdx.x; i < STRIPES * 2 * HDIM; i += 256) gpart[i] = 0.f;
    if (lo) atomicAdd(&nzhi, lo);
    if (ok) atomicAdd(&okbf, ok);
    __syncthreads();
    if (threadIdx.x == 0) {
        flags[0] = (nzhi == 0) ? 1 : 0;
        flags[1] = (okbf < 512) ? 1 : 0;
    }
}

// merged: ei/batch int32 conversion + in-degree count + weight transpose + bias
__global__ void conv_wt_all(const int* __restrict__ ei, const int* __restrict__ batch,
                            int* __restrict__ ei32, int* __restrict__ batch32,
                            int* __restrict__ cnt, int e2, int n,
                            const void* __restrict__ W1, const void* __restrict__ W2,
                            const void* __restrict__ Wf, const void* __restrict__ bf_,
                            bf16* __restrict__ W1T, bf16* __restrict__ W2T,
                            bf16* __restrict__ WfT, bf16* __restrict__ bfbf,
                            const int* __restrict__ flags) {
    const int S1 = 128 * 512, S2 = 512 * 512, S3 = 512 * 256;
    int i = blockIdx.x * 256 + threadIdx.x;
    int i64 = flags[0];
    bool f32 = flags[1] != 0;
    if (i < e2) {
        int v = i64 ? (int)((const long long*)ei)[i] : ei[i];
        ei32[i] = v;
        if (i >= e2 / 2) atomicAdd(&cnt[v], 1);   // cols half
    } else if (i < e2 + n) {
        int j = i - e2;
        batch32[j] = i64 ? (int)((const long long*)batch)[j] : batch[j];
    } else {
        int idx = i - e2 - n;
        if (idx < S1) {
            int nn = idx / 128, k = idx - nn * 128;   // K=128, Nn=512
            float v = f32 ? ((const float*)W1)[(size_t)k * 512 + nn]
                          : __bfloat162float(((const bf16*)W1)[(size_t)k * 512 + nn]);
            W1T[idx] = __float2bfloat16(v);
        } else if (idx < S1 + S2) {
            int t = idx - S1;
            int nn = t / 512, k = t - nn * 512;       // K=512, Nn=512
            float v = f32 ? ((const float*)W2)[(size_t)k * 512 + nn]
                          : __bfloat162float(((const bf16*)W2)[(size_t)k * 512 + nn]);
            W2T[t] = __float2bfloat16(v);
        } else if (idx < S1 + S2 + S3) {
            int t = idx - S1 - S2;
            int nn = t / 512, k = t - nn * 512;       // K=512, Nn=256
            float v = f32 ? ((const float*)Wf)[(size_t)k * 256 + nn]
                          : __bfloat162float(((const bf16*)Wf)[(size_t)k * 256 + nn]);
            WfT[t] = __float2bfloat16(v);
        } else if (idx < S1 + S2 + S3 + 256) {
            int t = idx - S1 - S2 - S3;
            float v = f32 ? ((const float*)bf_)[t]
                          : __bfloat162float(((const bf16*)bf_)[t]);
            bfbf[t] = __float2bfloat16(v);
        }
    }
}

// ---------------- parallel exclusive scan (3 kernels, 512 elems/block) -----------
// scan_part also finalizes degrees (dinv/selfw) from the same counts it loads.
__global__ __launch_bounds__(256) void scan_part(
    const int* __restrict__ counts, int* __restrict__ offsets,
    int* __restrict__ bsum, float* __restrict__ dinv, float* __restrict__ selfw,
    int n)
{
    __shared__ int s[512];
    int b = blockIdx.x;
    int base = b * 512;
    int t = threadIdx.x;
    int c0 = (base + t       < n) ? counts[base + t]       : 0;
    int c1 = (base + t + 256 < n) ? counts[base + t + 256] : 0;
    s[t] = c0; s[t + 256] = c1;
    if (base + t < n) {
        float d = (float)c0 + 2.0f;
        dinv[base + t] = rsqrtf(d);
        selfw[base + t] = 2.0f / d;
    }
    if (base + t + 256 < n) {
        float d = (float)c1 + 2.0f;
        dinv[base + t + 256] = rsqrtf(d);
        selfw[base + t + 256] = 2.0f / d;
    }

    int offset = 1;
    for (int d = 256; d > 0; d >>= 1) {
        __syncthreads();
        if (t < d) {
            int ai = offset * (2 * t + 1) - 1;
            int bi = offset * (2 * t + 2) - 1;
            s[bi] += s[ai];
        }
        offset <<= 1;
    }
    __syncthreads();
    if (t == 0) { bsum[b] = s[511]; s[511] = 0; }
    for (int d = 1; d < 512; d <<= 1) {
        offset >>= 1;
        __syncthreads();
        if (t < d) {
            int ai = offset * (2 * t + 1) - 1;
            int bi = offset * (2 * t + 2) - 1;
            int tmp = s[ai]; s[ai] = s[bi]; s[bi] += tmp;
        }
    }
    __syncthreads();
    if (base + t < n)       offsets[base + t]       = s[t];
    if (base + t + 256 < n) offsets[base + t + 256] = s[t + 256];
}

__global__ __launch_bounds__(1024) void scan_tops(int* __restrict__ bsum, int nb) {
    __shared__ int s[1024];
    int t = threadIdx.x;
    s[t] = (t < nb) ? bsum[t] : 0;
    __syncthreads();
    for (int off = 1; off < 1024; off <<= 1) {
        int v = (t >= off) ? s[t - off] : 0;
        __syncthreads();
        s[t] += v;
        __syncthreads();
    }
    if (t < nb) bsum[t] = (t == 0) ? 0 : s[t - 1];   // exclusive
}

// scan_add dual-writes cursor = offsets so scatter needs no memset + no re-read
__global__ __launch_bounds__(256) void scan_add(
    int* __restrict__ offsets, const int* __restrict__ bsum,
    int* __restrict__ cursor, int n, int e)
{
    int b = blockIdx.x;
    int base = b * 512;
    int add = bsum[b];
    int t = threadIdx.x;
    if (base + t < n) {
        int v = offsets[base + t] + add;
        offsets[base + t] = v; cursor[base + t] = v;
    }
    if (base + t + 256 < n) {
        int v = offsets[base + t + 256] + add;
        offsets[base + t + 256] = v; cursor[base + t + 256] = v;
    }
    if (b == 0 && t == 0) offsets[n] = e;
}

// scatter edges into CSR order; cursor pre-seeded with start offsets
__global__ void scatter_edges(const int* __restrict__ rows, const int* __restrict__ cols,
                              int* __restrict__ cursor, const float* __restrict__ dinv,
                              EdgeRec* __restrict__ er, int e)
{
    int i = blockIdx.x * blockDim.x + threadIdx.x;
    if (i < e) {
        int d = cols[i];
        int r = rows[i];
        int pos = atomicAdd(&cursor[d], 1);
        EdgeRec rec;
        rec.src = r;
        rec.nm = dinv[d] * dinv[r];
        er[pos] = rec;
    }
}

// ---- pooled slot init: [max | min], each gn floats --------------------------------
__global__ __launch_bounds__(256) void pool_init2(float* __restrict__ pS, int total, int gn) {
    int i = blockIdx.x * 256 + threadIdx.x;
    if (i < total) pS[i] = (i >= gn) ? 3.0e38f : -3.0e38f;
}

// ---- pooled finalize: BN+leaky monotone-select, empty->0 --------------------------
__global__ __launch_bounds__(256) void pool_fin2(
    const float* __restrict__ pS, const float* __restrict__ scale,
    const float* __restrict__ shift, bf16* __restrict__ outQ, int gn)
{
    int i = blockIdx.x * 256 + threadIdx.x;
    if (i >= gn) return;
    int c = i & (HDIM - 1);
    float vmax = pS[i];
    float vmin = pS[(size_t)gn + i];
    float outv = 0.f;
    if (vmax > -2.9e38f) {
        float s = scale[c];
        float t = s * (s >= 0.f ? vmax : vmin) + shift[c];
        outv = t > 0.f ? t : SLOPE * t;
    }
    outQ[i] = __float2bfloat16(outv);
}

// ------ m97-style GEMM, BK=32, natural grid order, LDS XOR-swizzle ----------------
// T4 counted-vmcnt 2-deep pipeline (verified). Natural grid mapping is already
// XCD-optimal (round-8 lesson). POOL epilogue v2: per-row-half LDS partial copies
// (waves 0,1 vs 2,3 -> 4-thread/cell contention instead of 8), single global slot:
// straddling graphs -> global atomics (all writers), non-straddling -> unique
// plain store. Straddle and plain-store writers are disjoint -> no race.
#define GEMM_STAGE(boff, kk)                                                             \
    {                                                                                    \
        _Pragma("unroll")                                                                \
        for (int i_ = 0; i_ < 2; i_++) {                                                 \
            int c_ = wave * 2 + i_;                                                      \
            const bf16* ga_ = A  + (size_t)(m0 + c_ * 16 + lrow) * K + (kk) + lcol;      \
            const bf16* gb_ = BT + (size_t)(n0 + c_ * 16 + lrow) * K + (kk) + lcol;      \
            __builtin_amdgcn_global_load_lds(                                            \
                (const __attribute__((address_space(1))) unsigned*)ga_,                  \
                (__attribute__((address_space(3))) unsigned*)(smem + (boff) + c_ * 512), \
                16, 0, 0);                                                               \
            __builtin_amdgcn_global_load_lds(                                            \
                (const __attribute__((address_space(1))) unsigned*)gb_,                  \
                (__attribute__((address_space(3))) unsigned*)(smem + 8192 + (boff) + c_ * 512), \
                16, 0, 0);                                                               \
        }                                                                                \
    }

#define GEMM_COMPUTE(boff)                                                               \
    {                                                                                    \
        short8 a[4], b[4];                                                               \
        _Pragma("unroll")                                                                \
        for (int mi2 = 0; mi2 < 4; mi2++)                                                \
            a[mi2] = *(const short8*)&smem[(boff) + (wm + mi2 * 16 + r) * 32 + aoff];    \
        _Pragma("unroll")                                                                \
        for (int ni = 0; ni < 4; ni++)                                                   \
            b[ni] = *(const short8*)&smem[8192 + (boff) + (wn + ni * 16 + r) * 32 + aoff]; \
        _Pragma("unroll")                                                                \
        for (int mi2 = 0; mi2 < 4; mi2++)                                                \
            _Pragma("unroll")                                                            \
            for (int ni = 0; ni < 4; ni++)                                               \
                acc[mi2][ni] = __builtin_amdgcn_mfma_f32_16x16x32_bf16(                  \
                    a[mi2], b[ni], acc[mi2][ni], 0, 0, 0);                               \
    }

template<bool STATS, bool POOL>
__global__ __launch_bounds__(256, 4) void gemm_m97(
    const bf16* __restrict__ A, const bf16* __restrict__ BT,
    void* __restrict__ C, const bf16* __restrict__ bias,
    int M, int K, int N, const int* __restrict__ cf32,
    float* __restrict__ gpart, int MB,
    const int* __restrict__ batchp, float* __restrict__ pS, int gn_total)
{
    // layout: [0,4096)=As buf0, [4096,8192)=As buf1, [8192,12288)=Bs buf0,
    //         [12288,16384)=Bs buf1 — 32 KB, reused as C tile / pool partials
    __shared__ bf16 smem[16384];

    int NBN = N >> 7;
    int id = blockIdx.x;
    int grp = id / (8 * NBN);
    int loc = id - grp * 8 * NBN;
    int mi = loc & 7;
    int nblk = loc >> 3;
    int mblk = grp * 8 + mi;
    if (mblk >= MB) return;

    int tid = threadIdx.x;
    int wave = tid >> 6, lane = tid & 63, q = lane >> 4, r = lane & 15;
    int wm = (wave >> 1) * 64, wn = (wave & 1) * 64;
    int m0 = mblk * 128, n0 = nblk * 128;
    bool c32 = cf32 && *cf32;

    int lrow = lane >> 2;
    int lcol = (((lane & 3) ^ ((lane >> 3) & 3)) * 8);   // XOR-swizzled source chunk
    int aoff = (q ^ ((r >> 1) & 3)) * 8;                 // fragment-read swizzle

    f32x4 acc[4][4];
#pragma unroll
    for (int mi2 = 0; mi2 < 4; mi2++)
#pragma unroll
        for (int ni = 0; ni < 4; ni++)
            acc[mi2][ni] = {0.f, 0.f, 0.f, 0.f};

    const int nK = K >> 5;

    // prologue: fill buffer 0 (4 loads in flight; first loop iter waits via vmcnt(4))
    GEMM_STAGE(0, 0);

    int cur = 0;
    for (int t = 1; t < nK; ++t) {
        GEMM_STAGE(cur ^ 4096, t * 32);   // issue next tile (8 outstanding/wave)
        asm volatile("s_waitcnt vmcnt(4)" ::: "memory");   // prev tile landed
        __builtin_amdgcn_sched_barrier(0);
        __builtin_amdgcn_s_barrier();     // all waves: cur buffer fully resident
        __builtin_amdgcn_sched_barrier(0);
        GEMM_COMPUTE(cur);                // ds_read + 16 MFMA (next loads in flight)
        asm volatile("s_waitcnt lgkmcnt(0)" ::: "memory"); // my ds_reads done
        __builtin_amdgcn_sched_barrier(0);
        __builtin_amdgcn_s_barrier();     // all waves done reading cur -> reusable
        __builtin_amdgcn_sched_barrier(0);
        cur ^= 4096;
    }
    asm volatile("s_waitcnt vmcnt(0)" ::: "memory");       // last tile landed
    __builtin_amdgcn_sched_barrier(0);
    __builtin_amdgcn_s_barrier();
    __builtin_amdgcn_sched_barrier(0);
    GEMM_COMPUTE(cur);                    // last tile, no prefetch

    if constexpr (!POOL) {
        if (!c32) {
            // ---- vectorized epilogue: stage C tile in LDS, write 16B/lane ----
            __syncthreads();             // full drain: all waves done with As/Bs
#pragma unroll
            for (int mi2 = 0; mi2 < 4; mi2++) {
#pragma unroll
                for (int ni = 0; ni < 4; ni++) {
                    int lc = wn + ni * 16 + r;
                    float bv = bias ? __bfloat162float(bias[n0 + lc]) : 0.f;
#pragma unroll
                    for (int reg = 0; reg < 4; reg++) {
                        int lr = wm + mi2 * 16 + q * 4 + reg;
                        int bo = ((lr << 8) + (lc << 1)) ^ (q << 5);  // q-XOR
                        *(bf16*)((char*)smem + bo) = __float2bfloat16(acc[mi2][ni][reg] + bv);
                    }
                }
            }
            __syncthreads();
#pragma unroll
            for (int pss = 0; pss < 8; pss++) {
                int off = pss * 4096 + tid * 16;
                int row = off >> 8;
                int cb = off & 255;
                int rb = cb ^ (((row >> 2) & 3) << 5);   // un-swizzle
                f32x4 v = *(const f32x4*)((const char*)smem + (row << 8) + rb);
                int gm = m0 + row;
                if (gm < M)
                    *(f32x4*)((char*)C + (((size_t)gm * N + n0) << 1) + cb) = v;
            }
        } else {
            // f32 output path (head GEMM with f32 inputs): scalar stores
#pragma unroll
            for (int mi2 = 0; mi2 < 4; mi2++) {
#pragma unroll
                for (int ni = 0; ni < 4; ni++) {
                    int gn = n0 + wn + ni * 16 + r;
                    float bv = bias ? __bfloat162float(bias[gn]) : 0.f;
#pragma unroll
                    for (int reg = 0; reg < 4; reg++) {
                        int gm = m0 + wm + mi2 * 16 + q * 4 + reg;
                        if (gm < M)
                            ((float*)C)[(size_t)gm * N + gn] = acc[mi2][ni][reg] + bv;
                    }
                }
            }
        }
    }

    if constexpr (POOL) {
        // ---- fused max/min pooling partials (no C-write) ----
        int batchv[16];
#pragma unroll
        for (int mi2 = 0; mi2 < 4; mi2++)
#pragma unroll
            for (int reg = 0; reg < 4; reg++) {
                int gm = m0 + wm + mi2 * 16 + q * 4 + reg;
                batchv[mi2 * 4 + reg] = (gm < M) ? batchp[gm] : -1;
            }
        int gfirst = batchp[m0];
        int lastrow = (m0 + 127 < M) ? (m0 + 127) : (M - 1);
        int glast = batchp[lastrow];
        int ng = glast - gfirst + 1;
        bool home0 = (m0 == 0) || (batchp[m0 - 1] < gfirst);
        bool cont  = (m0 + 128 <= M - 1) && (batchp[m0 + 128] == glast);
        // two partial copies: waves {0,1} (rows 0-63) and {2,3} (rows 64-127)
        float* partH = (float*)smem + (wave >> 1) * 4096;   // 16 KB each
        float* partA = (float*)smem;
        float* partB = (float*)smem + 4096;
        float* smax = pS;
        float* smin = pS + (size_t)gn_total;
        __syncthreads();   // all waves done with As/Bs before smem reuse
        for (int gbase = 0; gbase < ng; gbase += 16) {
            int nwin = ng - gbase; if (nwin > 16) nwin = 16;
            for (int i = tid; i < nwin * 256; i += 256) {
                float sv = (i & 1) ? 3.0e38f : -3.0e38f;
                partA[i] = sv; partB[i] = sv;
            }
            __syncthreads();
#pragma unroll
            for (int ni = 0; ni < 4; ni++) {
                int lc = wn + ni * 16 + r;
                float cmax = 0.f, cmin = 0.f;
                int curg = -1;
#pragma unroll
                for (int t2 = 0; t2 < 16; t2++) {
                    int g2 = batchv[t2];
                    float v = acc[t2 >> 2][ni][t2 & 3];
                    if (g2 >= 0) {
                        if (g2 != curg) {
                            if (curg >= 0) {
                                int gi = curg - gfirst - gbase;
                                if (gi >= 0 && gi < nwin) {
                                    atomicMaxF(&partH[(gi * 128 + lc) * 2], cmax);
                                    atomicMinF(&partH[(gi * 128 + lc) * 2 + 1], cmin);
                                }
                            }
                            curg = g2; cmax = v; cmin = v;
                        } else {
                            cmax = fmaxf(cmax, v); cmin = fminf(cmin, v);
                        }
                    }
                }
                if (curg >= 0) {
                    int gi = curg - gfirst - gbase;
                    if (gi >= 0 && gi < nwin) {
                        atomicMaxF(&partH[(gi * 128 + lc) * 2], cmax);
                        atomicMinF(&partH[(gi * 128 + lc) * 2 + 1], cmin);
                    }
                }
            }
            __syncthreads();
            for (int i = tid; i < nwin * 256; i += 256) {
                int cell = i >> 1;
                int gi = cell >> 7, col = cell & 127;
                int g2 = gfirst + gbase + gi;
                float va = partA[i], vb = partB[i];
                size_t gidx = (size_t)g2 * N + n0 + col;
                bool straddle = ((g2 == gfirst) && !home0) || ((g2 == glast) && cont);
                if (i & 1) {
                    float v = fminf(va, vb);
                    if (straddle) atomicMinF(&smin[gidx], v); else smin[gidx] = v;
                } else {
                    float v = fmaxf(va, vb);
                    if (straddle) atomicMaxF(&smax[gidx], v); else smax[gidx] = v;
                }
            }
            __syncthreads();
        }
    }

    if constexpr (STATS) {
        float* base = gpart + (size_t)(mblk & (STRIPES - 1)) * 2 * HDIM;
#pragma unroll
        for (int ni = 0; ni < 4; ni++) {
            float cs = 0.f, cq = 0.f;
#pragma unroll
            for (int mi2 = 0; mi2 < 4; mi2++)
#pragma unroll
                for (int reg = 0; reg < 4; reg++) {
                    int gm = m0 + wm + mi2 * 16 + q * 4 + reg;
                    if (gm < M) {
                        float v = acc[mi2][ni][reg];
                        cs += v; cq += v * v;
                    }
                }
            // reduce over q (lanes r, r+16, r+32, r+48 share column wn+ni*16+r)
            cs += __shfl_xor(cs, 16, 64);
            cs += __shfl_xor(cs, 32, 64);
            cq += __shfl_xor(cq, 16, 64);
            cq += __shfl_xor(cq, 32, 64);
            if (q == 0) {
                int c = n0 + wn + ni * 16 + r;
                atomicAdd(&base[c], cs);
                atomicAdd(&base[HDIM + c], cq);
            }
        }
    }
}

// ----- persistent CSR aggregation, 128-dim input -----------------------------------
#define AGG_DIN_BODY(LOADV)                                                            \
    int dst = gw;                                                                      \
    if (dst < n) {                                                                     \
        int s0 = offsets[dst], s1 = offsets[dst + 1];                                  \
        float sw = selfw[dst];                                                         \
        float h0, h1; LOADV(dst, h0, h1);                                              \
        while (dst < n) {                                                              \
            int nd = dst + nw;                                                         \
            int ns0 = 0, ns1 = 0; float nsw = 0.f, nh0 = 0.f, nh1 = 0.f;               \
            if (nd < n) {                                                              \
                ns0 = offsets[nd]; ns1 = offsets[nd + 1]; nsw = selfw[nd];             \
                LOADV(nd, nh0, nh1);                                                   \
            }                                                                          \
            float a0 = sw * h0, a1 = sw * h1;                                          \
            int p = s0;                                                                \
            for (; p + 3 < s1; p += 4) {                                               \
                EdgeRec e0 = er[p], e1 = er[p + 1], e2 = er[p + 2], e3 = er[p + 3];    \
                float x0, y0, x1, y1, x2, y2, x3, y3;                                  \
                LOADV(e0.src, x0, y0); LOADV(e1.src, x1, y1);                          \
                LOADV(e2.src, x2, y2); LOADV(e3.src, x3, y3);                          \
                a0 += e0.nm * x0 + e1.nm * x1 + e2.nm * x2 + e3.nm * x3;               \
                a1 += e0.nm * y0 + e1.nm * y1 + e2.nm * y2 + e3.nm * y3;               \
            }                                                                          \
            int rem = s1 - p;                                                          \
            if (rem > 0) {                                                             \
                EdgeRec e0 = er[p], e1 = e0, e2 = e0;                                  \
                if (rem > 1) e1 = er[p + 1];                                           \
                if (rem > 2) e2 = er[p + 2];                                           \
                float x0, y0, x1 = 0.f, y1 = 0.f, x2 = 0.f, y2 = 0.f;                  \
                LOADV(e0.src, x0, y0);                                                 \
                if (rem > 1) LOADV(e1.src, x1, y1);                                    \
                if (rem > 2) LOADV(e2.src, x2, y2);                                    \
                a0 += e0.nm * x0; a1 += e0.nm * y0;                                    \
                if (rem > 1) { a0 += e1.nm * x1; a1 += e1.nm * y1; }                   \
                if (rem > 2) { a0 += e2.nm * x2; a1 += e2.nm * y2; }                   \
            }                                                                          \
            ((unsigned*)out)[(size_t)dst * 64 + lane] =                                \
                (unsigned)f2bfbits(a0) | ((unsigned)f2bfbits(a1) << 16);               \
            dst = nd; s0 = ns0; s1 = ns1; sw = nsw; h0 = nh0; h1 = nh1;                \
        }                                                                              \
    }

#define LOADF32(idx, a, b) { float2 v_ = ((const float2*)x)[(size_t)(idx) * 64 + lane]; \
                             a = v_.x; b = v_.y; }
#define LOADBF(idx, a, b)  { unsigned u_ = ((const unsigned*)x)[(size_t)(idx) * 64 + lane]; \
                             a = bf2f((short)(u_ & 0xFFFF)); b = bf2f((short)(u_ >> 16)); }

__global__ __launch_bounds__(256) void agg_csr_din(
    const void* __restrict__ x, const int* __restrict__ offsets,
    const EdgeRec* __restrict__ er, const float* __restrict__ selfw,
    bf16* __restrict__ out, int n, const int* __restrict__ flags)
{
    int wave = threadIdx.x >> 6, lane = threadIdx.x & 63;
    int gw = blockIdx.x * 4 + wave;
    int nw = gridDim.x * 4;
    bool f32 = flags[1] != 0;
    if (f32) { AGG_DIN_BODY(LOADF32) } else { AGG_DIN_BODY(LOADBF) }
}

// -- persistent CSR aggregation (512-dim) with fused BN-affine+leaky ---------------
__device__ inline void bnlk8(const short8& v, const float* sc, const float* sh,
                             float* t) {
#pragma unroll
    for (int j = 0; j < 8; j++) {
        float u = sc[j] * bf2f(v[j]) + sh[j];
        t[j] = u > 0.f ? u : SLOPE * u;
    }
}

__global__ __launch_bounds__(256) void agg_csr_bn(
    const bf16* __restrict__ h, const int* __restrict__ offsets,
    const EdgeRec* __restrict__ er, const float* __restrict__ selfw,
    const float* __restrict__ scale, const float* __restrict__ shift,
    bf16* __restrict__ y, int n)
{
    int wave = threadIdx.x >> 6, lane = threadIdx.x & 63;
    int f0 = lane * 8;
    int gw = blockIdx.x * 4 + wave;
    int nw = gridDim.x * 4;

    float sc[8], sh[8];
#pragma unroll
    for (int j = 0; j < 8; j++) { sc[j] = scale[f0 + j]; sh[j] = shift[f0 + j]; }

    int dst = gw;
    if (dst >= n) return;
    int s0 = offsets[dst], s1 = offsets[dst + 1];
    float sw = selfw[dst];
    short8 hv = *(const short8*)(h + (size_t)dst * HDIM + f0);

    while (dst < n) {
        int nd = dst + nw;
        int ns0 = 0, ns1 = 0; float nsw = 0.f; short8 nhv = {};
        if (nd < n) {
            ns0 = offsets[nd]; ns1 = offsets[nd + 1]; nsw = selfw[nd];
            nhv = *(const short8*)(h + (size_t)nd * HDIM + f0);
        }

        float acc[8], t[8];
        bnlk8(hv, sc, sh, t);
#pragma unroll
        for (int j = 0; j < 8; j++) acc[j] = sw * t[j];

        int p = s0;
        for (; p + 3 < s1; p += 4) {
            EdgeRec e0 = er[p], e1 = er[p + 1], e2 = er[p + 2], e3 = er[p + 3];
            short8 v0 = *(const short8*)(h + (size_t)e0.src * HDIM + f0);
            short8 v1 = *(const short8*)(h + (size_t)e1.src * HDIM + f0);
            short8 v2 = *(const short8*)(h + (size_t)e2.src * HDIM + f0);
            short8 v3 = *(const short8*)(h + (size_t)e3.src * HDIM + f0);
            float t0[8], t1[8], t2[8], t3[8];
            bnlk8(v0, sc, sh, t0); bnlk8(v1, sc, sh, t1);
            bnlk8(v2, sc, sh, t2); bnlk8(v3, sc, sh, t3);
#pragma unroll
            for (int j = 0; j < 8; j++)
                acc[j] += e0.nm * t0[j] + e1.nm * t1[j] + e2.nm * t2[j] + e3.nm * t3[j];
        }
        int rem = s1 - p;
        if (rem > 0) {
            EdgeRec e0 = er[p], e1 = e0, e2 = e0;
            if (rem > 1) e1 = er[p + 1];
            if (rem > 2) e2 = er[p + 2];
            short8 v0 = *(const short8*)(h + (size_t)e0.src * HDIM + f0);
            short8 v1 = {}, v2 = {};
            if (rem > 1) v1 = *(const short8*)(h + (size_t)e1.src * HDIM + f0);
            if (rem > 2) v2 = *(const short8*)(h + (size_t)e2.src * HDIM + f0);
            float t0[8];
            bnlk8(v0, sc, sh, t0);
#pragma unroll
            for (int j = 0; j < 8; j++) acc[j] += e0.nm * t0[j];
            if (rem > 1) {
                float t1[8]; bnlk8(v1, sc, sh, t1);
#pragma unroll
                for (int j = 0; j < 8; j++) acc[j] += e1.nm * t1[j];
            }
            if (rem > 2) {
                float t2[8]; bnlk8(v2, sc, sh, t2);
#pragma unroll
                for (int j = 0; j < 8; j++) acc[j] += e2.nm * t2[j];
            }
        }

        short8 o;
#pragma unroll
        for (int j = 0; j < 8; j++) ((bf16*)&o)[j] = __float2bfloat16(acc[j]);
        *(short8*)(y + (size_t)dst * HDIM + f0) = o;

        dst = nd; s0 = ns0; s1 = ns1; sw = nsw; hv = nhv;
    }
}

// ------ BN coeffs from striped partials; re-zeros gpart for the next layer --------
__global__ void bn_final(float* __restrict__ gpart,
                         const void* __restrict__ gamma, const void* __restrict__ beta,
                         float* __restrict__ scale, float* __restrict__ shift,
                         float invN, const int* __restrict__ flags)
{
    int f = threadIdx.x;
    float s = 0.f, q = 0.f;
#pragma unroll
    for (int k = 0; k < STRIPES; k++) {
        s += gpart[(size_t)k * 2 * HDIM + f];
        q += gpart[(size_t)k * 2 * HDIM + HDIM + f];
        gpart[(size_t)k * 2 * HDIM + f] = 0.f;
        gpart[(size_t)k * 2 * HDIM + HDIM + f] = 0.f;
    }
    float g = flags[1] ? ((const float*)gamma)[f]
                       : __bfloat162float(((const bf16*)gamma)[f]);
    float b = flags[1] ? ((const float*)beta)[f]
                       : __bfloat162float(((const bf16*)beta)[f]);
    float mu = s * invN;
    float var = fmaxf(q * invN - mu * mu, 0.f);
    float inv = rsqrtf(var + BN_EPS);
    float sc = g * inv;
    scale[f] = sc;
    shift[f] = b - mu * sc;
}

// ---------------- orchestration --------------------------------------------------
extern "C" void kernel_launch(void* const* d_in, const int* in_sizes, int n_in,
                              void* d_out, int out_size, void* d_ws, size_t ws_size,
                              hipStream_t stream)
{
    const void* x     = d_in[0];
    const int*  ei    = (const int*)d_in[1];
    const int*  batch = (const int*)d_in[2];
    // d_in[4]=b1, d_in[8]=b2 cancel in training-mode BatchNorm — unused.

    const int N   = in_sizes[2];
    const int E   = in_sizes[1] / 2;
    const int DIN = 128;
    const int OUT = 256;
    const int G   = out_size / OUT;
    const int Mp  = (N + 127) & ~127;
    const int MB  = Mp / 128;
    const int MB8 = (MB + 7) & ~7;

    // workspace carve — ~238 MB
    char* p = (char*)d_ws;
    bf16* B1     = (bf16*)p;  p += (size_t)Mp * HDIM * sizeof(bf16);
    bf16* B2     = (bf16*)p;  p += (size_t)Mp * HDIM * sizeof(bf16);
    bf16* Q      = (bf16*)p;  p += (size_t)Mp * DIN * sizeof(bf16);
    bf16* W1T    = (bf16*)p;  p += (size_t)HDIM * DIN * sizeof(bf16);
    bf16* W2T    = (bf16*)p;  p += (size_t)HDIM * HDIM * sizeof(bf16);
    bf16* WfT    = (bf16*)p;  p += (size_t)OUT * HDIM * sizeof(bf16);
    bf16* bfbf   = (bf16*)p;  p += 512 * sizeof(bf16);
    int* ei32    = (int*)p;   p += (size_t)2 * E * sizeof(int);
    int* batch32 = (int*)p;   p += (size_t)N * sizeof(int);
    float* dinv  = (float*)p; p += (size_t)N * sizeof(float);
    float* selfw = (float*)p; p += (size_t)N * sizeof(float);
    int* offsets = (int*)p;   p += (size_t)(N + 4) * sizeof(int);
    int* cursor  = (int*)p;   p += (size_t)N * sizeof(int);
    EdgeRec* er  = (EdgeRec*)p; p += (size_t)E * sizeof(EdgeRec);
    int* bsum    = (int*)p;   p += 1024 * sizeof(int);
    float* gpart = (float*)p; p += (size_t)STRIPES * 2 * HDIM * sizeof(float);
    float* sc1   = (float*)p; p += HDIM * sizeof(float);
    float* sh1   = (float*)p; p += HDIM * sizeof(float);
    float* sc2   = (float*)p; p += HDIM * sizeof(float);
    float* sh2   = (float*)p; p += HDIM * sizeof(float);
    int* flags   = (int*)p;   p += 4 * sizeof(int);

    // pooled slot buffers live in B2's region (dead after agg_csr_bn reads it):
    // [max | min], each G*HDIM floats = 16.7 MB total
    float* pS = (float*)B2;
    const int GN = G * HDIM;

    // ---- detection (+gpart zero) + fused conversions + degree count ----
    detect_types<<<1, 256, 0, stream>>>(ei, (const unsigned*)x, flags, gpart);
    hipMemsetAsync(cursor, 0, (size_t)N * sizeof(int), stream);
    {
        const int WTOT = 128 * 512 + 512 * 512 + 512 * 256 + 256;
        conv_wt_all<<<(2 * E + N + WTOT + 255) / 256, 256, 0, stream>>>(
            ei, batch, ei32, batch32, cursor, 2 * E, N,
            d_in[3], d_in[7], d_in[11], d_in[12], W1T, W2T, WfT, bfbf, flags);
    }

    const int* rows = ei32;
    const int* cols = ei32 + E;

    // ---- CSR + degrees (fused into scan_part) + packed edge records ----
    int nb = (N + 511) / 512;
    scan_part<<<nb, 256, 0, stream>>>(cursor, offsets, bsum, dinv, selfw, N);
    scan_tops<<<1, 1024, 0, stream>>>(bsum, nb);
    scan_add<<<nb, 256, 0, stream>>>(offsets, bsum, cursor, N, E);
    scatter_edges<<<(E + 255) / 256, 256, 0, stream>>>(rows, cols, cursor, dinv, er, E);

    int gemm_blocks = MB8 * (HDIM / 128);

    // ---- layer 1: aggregate x (agg is linear), GEMM w/ fused stats ----
    agg_csr_din<<<2048, 256, 0, stream>>>(x, offsets, er, selfw, Q, N, flags);
    gemm_m97<true, false><<<gemm_blocks, 256, 0, stream>>>(
        Q, W1T, B2, nullptr, N, DIN, HDIM, nullptr, gpart, MB,
        nullptr, nullptr, 0);
    bn_final<<<1, HDIM, 0, stream>>>(gpart, d_in[5], d_in[6], sc1, sh1, 1.0f / N, flags);

    // ---- layer 2: aggregate conv1 w/ fused BN+leaky, then GEMM with fused stats
    //      AND fused pooling partials (single slot, straddle-aware atomics) ----
    agg_csr_bn<<<2048, 256, 0, stream>>>(B2, offsets, er, selfw, sc1, sh1, B1, N);
    pool_init2<<<(2 * GN + 255) / 256, 256, 0, stream>>>(pS, 2 * GN, GN);
    gemm_m97<true, true><<<gemm_blocks, 256, 0, stream>>>(
        B1, W2T, nullptr, nullptr, N, HDIM, HDIM, nullptr, gpart, MB,
        batch32, pS, GN);
    bn_final<<<1, HDIM, 0, stream>>>(gpart, d_in[9], d_in[10], sc2, sh2, 1.0f / N, flags);

    // ---- pooled finalize (BN+leaky monotone) + head GEMM ----
    pool_fin2<<<(GN + 255) / 256, 256, 0, stream>>>(pS, sc2, sh2, Q, GN);
    gemm_m97<false, false><<<(G / 128) * (OUT / 128), 256, 0, stream>>>(
        Q, WfT, d_out, bfbf, G, HDIM, OUT, flags + 1, nullptr, G / 128,
        nullptr, nullptr, 0);
}